// Round 16
// baseline (764.486 us; speedup 1.0000x reference)
//
#include <hip/hip_runtime.h>

#define N_NODES 100000
#define N_EDGES 800000
#define N_GRAPH 256
#define MP      100096   // 391 * 256, padded M
#define NH      512

typedef __bf16 bf16x4v __attribute__((ext_vector_type(4)));
typedef __bf16 bf16x8v __attribute__((ext_vector_type(8)));
typedef float  f32x4   __attribute__((ext_vector_type(4)));
typedef float  f32x2   __attribute__((ext_vector_type(2)));

__device__ __forceinline__ void gload_lds16(const void* g, void* l) {
  __builtin_amdgcn_global_load_lds((const __attribute__((address_space(1))) void*)g,
                                   (__attribute__((address_space(3))) void*)l, 16, 0, 0);
}

// order-preserving fp32 <-> uint32 encoding for atomicMax
__device__ __forceinline__ unsigned enc_f32(float f) {
  unsigned u = __float_as_uint(f);
  return (u & 0x80000000u) ? ~u : (u | 0x80000000u);
}
__device__ __forceinline__ float dec_f32(unsigned u) {
  return (u & 0x80000000u) ? __uint_as_float(u & 0x7FFFFFFFu) : __uint_as_float(~u);
}

// ---------------- cast x (fp32) -> padded bf16 [MP][512] ----------------
__global__ __launch_bounds__(256) void castx_kernel(const float* __restrict__ x,
                                                    __bf16* __restrict__ xb) {
  const size_t i = (size_t)blockIdx.x * 256 + threadIdx.x;   // 8-elem chunk id
  const size_t row = i >> 6;
  const int c = (int)(i & 63) * 8;
  if (row >= MP) return;
  bf16x8v o;
  if (row < N_NODES) {
    const float* p = x + row * 512 + c;
    f32x4 a = *(const f32x4*)p;
    f32x4 b = *(const f32x4*)(p + 4);
    o[0]=(__bf16)a[0]; o[1]=(__bf16)a[1]; o[2]=(__bf16)a[2]; o[3]=(__bf16)a[3];
    o[4]=(__bf16)b[0]; o[5]=(__bf16)b[1]; o[6]=(__bf16)b[2]; o[7]=(__bf16)b[3];
  } else {
    for (int j = 0; j < 8; ++j) o[j] = (__bf16)0.0f;
  }
  *(bf16x8v*)(xb + row * 512 + c) = o;
}

// ---------------- weight transpose: W[K][N] fp32 -> BT[N][K] bf16 ----------------
__global__ __launch_bounds__(256) void transpose_kernel(const float* __restrict__ W,
                                                        __bf16* __restrict__ BT,
                                                        int K, int Nn) {
  __shared__ float tile[32][33];
  const int bx = blockIdx.x;   // n tile
  const int by = blockIdx.y;   // k tile
  const int tx = threadIdx.x & 31;
  const int ty = threadIdx.x >> 5;   // 0..7
  for (int j = 0; j < 4; ++j) {
    int k = by * 32 + ty + j * 8;
    int n = bx * 32 + tx;
    tile[ty + j * 8][tx] = W[(size_t)k * Nn + n];
  }
  __syncthreads();
  for (int j = 0; j < 4; ++j) {
    int n = bx * 32 + ty + j * 8;
    int k = by * 32 + tx;
    BT[(size_t)n * K + k] = (__bf16)tile[tx][ty + j * 8];
  }
}

// ---------------- CSR build ----------------
__global__ __launch_bounds__(256) void degree_kernel(const int* __restrict__ dst,
                                                     int* __restrict__ deg) {
  int e = blockIdx.x * 256 + threadIdx.x;
  if (e < N_EDGES) atomicAdd(&deg[dst[e]], 1);
}

__global__ __launch_bounds__(256) void scan1_kernel(const int* __restrict__ deg,
                                                    int* __restrict__ rs,
                                                    int* __restrict__ bsum, int n) {
  __shared__ int lds[256];
  const int b = blockIdx.x, t = threadIdx.x;
  const int base = b * 1024 + t * 4;
  int v[4];
  for (int j = 0; j < 4; ++j) v[j] = (base + j < n) ? deg[base + j] : 0;
  int tsum = v[0] + v[1] + v[2] + v[3];
  lds[t] = tsum;
  __syncthreads();
  for (int off = 1; off < 256; off <<= 1) {
    int x = 0;
    if (t >= off) x = lds[t - off];
    __syncthreads();
    lds[t] += x;
    __syncthreads();
  }
  int run = lds[t] - tsum;   // exclusive prefix of this thread
  for (int j = 0; j < 4; ++j) {
    if (base + j < n) rs[base + j] = run;
    run += v[j];
  }
  if (t == 255) bsum[b] = lds[255];
}

__global__ void scan2_kernel(int* bsum, int nb) {
  if (threadIdx.x == 0 && blockIdx.x == 0) {
    int run = 0;
    for (int i = 0; i < nb; ++i) { int v = bsum[i]; bsum[i] = run; run += v; }
  }
}

__global__ __launch_bounds__(256) void scan3_kernel(int* __restrict__ rs,
                                                    const int* __restrict__ bsum,
                                                    int* __restrict__ cursor, int n) {
  int i = blockIdx.x * 256 + threadIdx.x;
  if (i < n) {
    int v = rs[i] + bsum[i >> 10];
    rs[i] = v;
    cursor[i] = v;
  } else if (i == n) {
    rs[n] = N_EDGES;
  }
}

__global__ __launch_bounds__(256) void scatter_kernel(const int* __restrict__ src,
                                                      const int* __restrict__ dst,
                                                      int* __restrict__ cursor,
                                                      int* __restrict__ csr) {
  int e = blockIdx.x * 256 + threadIdx.x;
  if (e < N_EDGES) {
    int slot = atomicAdd(&cursor[dst[e]], 1);
    csr[slot] = src[e];
  }
}

// ---------------- aggregate (fp8 gather): agg[n] = sum_{e: dst==n} h8[src[e]] ------------
__global__ __launch_bounds__(256) void aggregate8_kernel(const unsigned* __restrict__ h8,
                                                         const int* __restrict__ rs,
                                                         const int* __restrict__ csr,
                                                         __bf16* __restrict__ agg) {
  const int node = blockIdx.x * 4 + (threadIdx.x >> 6);
  if (node >= N_NODES) return;
  const int lane = threadIdx.x & 63;
  const int s = rs[node], e = rs[node + 1];
  float acc[8] = {0.f,0.f,0.f,0.f,0.f,0.f,0.f,0.f};
  const size_t lofs = (size_t)lane * 2;     // 8 fp8 = 2 dwords per lane
  for (int i = s; i < e; i += 4) {
    const int i1 = (i + 1 < e) ? i + 1 : i;
    const int i2 = (i + 2 < e) ? i + 2 : i;
    const int i3 = (i + 3 < e) ? i + 3 : i;
    const float w1 = (i + 1 < e) ? 1.f : 0.f;
    const float w2 = (i + 2 < e) ? 1.f : 0.f;
    const float w3 = (i + 3 < e) ? 1.f : 0.f;
    const int n0 = csr[i], n1 = csr[i1], n2 = csr[i2], n3 = csr[i3];
    uint2 u0 = *(const uint2*)(h8 + (size_t)n0 * 128 + lofs);
    uint2 u1 = *(const uint2*)(h8 + (size_t)n1 * 128 + lofs);
    uint2 u2 = *(const uint2*)(h8 + (size_t)n2 * 128 + lofs);
    uint2 u3 = *(const uint2*)(h8 + (size_t)n3 * 128 + lofs);

    f32x2 a, b, c, d;
    a = __builtin_amdgcn_cvt_pk_f32_fp8((int)u0.x, false);
    b = __builtin_amdgcn_cvt_pk_f32_fp8((int)u0.x, true);
    c = __builtin_amdgcn_cvt_pk_f32_fp8((int)u0.y, false);
    d = __builtin_amdgcn_cvt_pk_f32_fp8((int)u0.y, true);
    acc[0]+=a[0]; acc[1]+=a[1]; acc[2]+=b[0]; acc[3]+=b[1];
    acc[4]+=c[0]; acc[5]+=c[1]; acc[6]+=d[0]; acc[7]+=d[1];

    a = __builtin_amdgcn_cvt_pk_f32_fp8((int)u1.x, false);
    b = __builtin_amdgcn_cvt_pk_f32_fp8((int)u1.x, true);
    c = __builtin_amdgcn_cvt_pk_f32_fp8((int)u1.y, false);
    d = __builtin_amdgcn_cvt_pk_f32_fp8((int)u1.y, true);
    acc[0]=fmaf(w1,a[0],acc[0]); acc[1]=fmaf(w1,a[1],acc[1]);
    acc[2]=fmaf(w1,b[0],acc[2]); acc[3]=fmaf(w1,b[1],acc[3]);
    acc[4]=fmaf(w1,c[0],acc[4]); acc[5]=fmaf(w1,c[1],acc[5]);
    acc[6]=fmaf(w1,d[0],acc[6]); acc[7]=fmaf(w1,d[1],acc[7]);

    a = __builtin_amdgcn_cvt_pk_f32_fp8((int)u2.x, false);
    b = __builtin_amdgcn_cvt_pk_f32_fp8((int)u2.x, true);
    c = __builtin_amdgcn_cvt_pk_f32_fp8((int)u2.y, false);
    d = __builtin_amdgcn_cvt_pk_f32_fp8((int)u2.y, true);
    acc[0]=fmaf(w2,a[0],acc[0]); acc[1]=fmaf(w2,a[1],acc[1]);
    acc[2]=fmaf(w2,b[0],acc[2]); acc[3]=fmaf(w2,b[1],acc[3]);
    acc[4]=fmaf(w2,c[0],acc[4]); acc[5]=fmaf(w2,c[1],acc[5]);
    acc[6]=fmaf(w2,d[0],acc[6]); acc[7]=fmaf(w2,d[1],acc[7]);

    a = __builtin_amdgcn_cvt_pk_f32_fp8((int)u3.x, false);
    b = __builtin_amdgcn_cvt_pk_f32_fp8((int)u3.x, true);
    c = __builtin_amdgcn_cvt_pk_f32_fp8((int)u3.y, false);
    d = __builtin_amdgcn_cvt_pk_f32_fp8((int)u3.y, true);
    acc[0]=fmaf(w3,a[0],acc[0]); acc[1]=fmaf(w3,a[1],acc[1]);
    acc[2]=fmaf(w3,b[0],acc[2]); acc[3]=fmaf(w3,b[1],acc[3]);
    acc[4]=fmaf(w3,c[0],acc[4]); acc[5]=fmaf(w3,c[1],acc[5]);
    acc[6]=fmaf(w3,d[0],acc[6]); acc[7]=fmaf(w3,d[1],acc[7]);
  }
  bf16x8v o;
#pragma unroll
  for (int j = 0; j < 8; ++j) o[j] = (__bf16)acc[j];
  *(bf16x8v*)(agg + (size_t)node * 512 + (size_t)lane * 8) = o;
}

// ---------------- aggregate (layer 1, rank-8): aggS[n] = sum sim0[src] ----------------
__global__ __launch_bounds__(256) void aggsim_kernel(const float* __restrict__ sim,
                                                     const int* __restrict__ rs,
                                                     const int* __restrict__ csr,
                                                     float* __restrict__ aggS) {
  const int node = blockIdx.x * 256 + threadIdx.x;
  if (node >= N_NODES) return;
  f32x4 a0 = f32x4{0.f,0.f,0.f,0.f}, a1 = f32x4{0.f,0.f,0.f,0.f};
  const int s = rs[node], e = rs[node + 1];
  for (int i = s; i < e; ++i) {
    const int sn = csr[i];
    a0 += *(const f32x4*)(sim + (size_t)sn * 8);
    a1 += *(const f32x4*)(sim + (size_t)sn * 8 + 4);
  }
  *(f32x4*)(aggS + (size_t)node * 8) = a0;
  *(f32x4*)(aggS + (size_t)node * 8 + 4) = a1;
}

// ---------------- UV: U[m] = mem0[m] @ W1_1[0:512], V[m] = mem0[m] @ W1_1[512:1024] -----
__global__ __launch_bounds__(512) void uv_kernel(const float* __restrict__ mem,
                                                 const float* __restrict__ w1,
                                                 float* __restrict__ UV) {
  const int mu = blockIdx.x;        // 0..15
  const int c  = threadIdx.x;       // 0..511
  const int m = mu & 7, half = mu >> 3;
  const float* wbase = w1 + (size_t)(half * 512) * 512;
  const float* mrow  = mem + (size_t)m * 512;
  float acc = 0.f;
  for (int k = 0; k < 512; ++k) acc += mrow[k] * wbase[(size_t)k * 512 + c];
  UV[(size_t)mu * 512 + c] = acc;
}

// ---------------- z1y: y1 = relu(sim0 @ U + aggS @ V + b1), [N,512] bf16 ----------------
__global__ __launch_bounds__(256) void z1y_kernel(const float* __restrict__ sim,
                                                  const float* __restrict__ aggS,
                                                  const float* __restrict__ UV,
                                                  const float* __restrict__ b1,
                                                  __bf16* __restrict__ y) {
  __shared__ float suv[16 * 512];   // 32KB
  __shared__ float sb[512];
  const int tid = threadIdx.x;
  for (int i = tid; i < 8192; i += 256) suv[i] = UV[i];
  for (int i = tid; i < 512; i += 256) sb[i] = b1[i];
  __syncthreads();
  const int node = blockIdx.x * 4 + (tid >> 6);
  if (node >= N_NODES) return;
  const int lane = tid & 63;
  f32x4 s0 = *(const f32x4*)(sim + (size_t)node * 8);
  f32x4 s1 = *(const f32x4*)(sim + (size_t)node * 8 + 4);
  f32x4 a0 = *(const f32x4*)(aggS + (size_t)node * 8);
  f32x4 a1 = *(const f32x4*)(aggS + (size_t)node * 8 + 4);
  float sv[8] = {s0[0],s0[1],s0[2],s0[3],s1[0],s1[1],s1[2],s1[3]};
  float av[8] = {a0[0],a0[1],a0[2],a0[3],a1[0],a1[1],a1[2],a1[3]};
  __bf16* yrow = y + (size_t)node * 512;
#pragma unroll
  for (int j = 0; j < 8; ++j) {
    const int c = lane + j * 64;
    float acc = sb[c];
#pragma unroll
    for (int m = 0; m < 8; ++m) {
      acc += sv[m] * suv[m * 512 + c];
      acc += av[m] * suv[(8 + m) * 512 + c];
    }
    yrow[c] = (__bf16)fmaxf(acc, 0.f);
  }
}

// ---------------- GEMM 128x128, BK=32, ring-4 depth-3, 64KB LDS -> 2 blocks/CU ----------
// C[M][512] = relu?( A @ BT^T + bias ), bf16 in/out, fp32 acc.
// H8:  epilogue additionally emits fp8-e4m3 copy of C (LDS repack; ring dead post-loop).
// SIM: epilogue does NOT write C; instead computes partial sim scores
//      simraw[row][m] += sum_cols relu(z)[row][col] * memf[m][col]  (this block's cols),
//      via 16-lane shfl reduction + atomicAdd (contention = 4 blocks per address).
template<int KTOT, bool SPLIT, bool RELU, bool H8, bool SIM>
__global__ __launch_bounds__(256, 2) void gemm128_kernel(const __bf16* __restrict__ A1,
                                                         const __bf16* __restrict__ A2,
                                                         const __bf16* __restrict__ BT,
                                                         const float* __restrict__ bias,
                                                         __bf16* __restrict__ C,
                                                         unsigned* __restrict__ C8,
                                                         const float* __restrict__ memf,
                                                         float* __restrict__ simraw) {
  extern __shared__ char smem[];
  __bf16* As = (__bf16*)smem;              // 4 slots * 8KB = 32KB
  __bf16* Bs = (__bf16*)(smem + 32768);    // 32KB
  float* memS = (float*)(smem + 65536);    // [8][128] fp32 (SIM only)
  const int tid  = threadIdx.x;
  const int wid  = tid >> 6;     // 0..3
  const int lane = tid & 63;
  const int wm = wid >> 1;       // 0..1
  const int wn = wid & 1;        // 0..1
  const int srow = tid >> 2;     // 0..63 (row within 64-row half)
  const int scol = ((tid & 3) ^ ((tid >> 3) & 3)) * 8;   // inverse-swizzled source chunk
  const int rl  = lane & 15;
  const int rdk = (((lane >> 4) ^ ((lane >> 1) & 3)) * 8);  // swizzled read chunk

  // XCD-aware bijective remap (1564 = 4*196 + 4*195); the 4 N-tiles of a tm share an XCD
  const int bid = blockIdx.x;
  const int xcd = bid & 7, pos = bid >> 3;
  const int idx = (xcd < 4) ? (xcd * 196 + pos) : (784 + (xcd - 4) * 195 + pos);
  const int tm = idx >> 2, tn = idx & 3;

  constexpr int NT = KTOT / 32;

  // SIM: stage this block's mem slice [8][tn*128 .. +128] (loads drain at ds_write,
  // so the ring's counted vmcnt ledger is unaffected)
  if (SIM) {
    const int m = tid >> 5, c4 = (tid & 31) * 4;
    f32x4 v = *(const f32x4*)(memf + (size_t)m * 512 + tn * 128 + c4);
    *(f32x4*)(memS + m * 128 + c4) = v;
  }

  f32x4 acc[4][4];
#pragma unroll
  for (int mi = 0; mi < 4; ++mi)
#pragma unroll
    for (int ni = 0; ni < 4; ++ni)
      acc[mi][ni] = f32x4{0.f, 0.f, 0.f, 0.f};

  auto stage = [&](int tk) {
    const int slot = tk & 3;
    const __bf16* Ap = A1;
    int kc = tk * 32;
    if (SPLIT && tk >= NT / 2) { Ap = A2; kc -= 512; }
#pragma unroll
    for (int j = 0; j < 2; ++j) {
      const __bf16* g = Ap + (size_t)(tm * 128 + j * 64 + srow) * NH + (kc + scol);
      gload_lds16(g, (char*)As + slot * 8192 + j * 4096 + wid * 1024);
    }
#pragma unroll
    for (int j = 0; j < 2; ++j) {
      const __bf16* g = BT + (size_t)(tn * 128 + j * 64 + srow) * KTOT + (tk * 32 + scol);
      gload_lds16(g, (char*)Bs + slot * 8192 + j * 4096 + wid * 1024);
    }
  };

  // prologue: fill 3 slots (12 loads in flight)
  stage(0); stage(1); stage(2);

  for (int tk = 0; tk < NT; ++tk) {
    if (tk < NT - 2)       asm volatile("s_waitcnt vmcnt(8)" ::: "memory");
    else if (tk == NT - 2) asm volatile("s_waitcnt vmcnt(4)" ::: "memory");
    else                   asm volatile("s_waitcnt vmcnt(0)" ::: "memory");
    __builtin_amdgcn_s_barrier();            // tile tk landed, tile tk-1 consumed
    asm volatile("" ::: "memory");           // pin LDS ops after the barrier

    if (tk + 3 < NT) stage(tk + 3);          // overwrites slot (tk-1)&3 -- safe post-barrier

    const int slot = tk & 3;
    const __bf16* a0 = As + slot * 4096 + (wm * 64 + rl) * 32 + rdk;
    const __bf16* b0 = Bs + slot * 4096 + (wn * 64 + rl) * 32 + rdk;
    bf16x8v av[4], bv[4];
#pragma unroll
    for (int mi = 0; mi < 4; ++mi) av[mi] = *(const bf16x8v*)(a0 + mi * 16 * 32);
#pragma unroll
    for (int ni = 0; ni < 4; ++ni) bv[ni] = *(const bf16x8v*)(b0 + ni * 16 * 32);

    __builtin_amdgcn_s_setprio(1);
#pragma unroll
    for (int mi = 0; mi < 4; ++mi)
#pragma unroll
      for (int ni = 0; ni < 4; ++ni)
        acc[mi][ni] = __builtin_amdgcn_mfma_f32_16x16x32_bf16(av[mi], bv[ni], acc[mi][ni], 0, 0, 0);
    __builtin_amdgcn_s_setprio(0);
  }

  const int rg = (lane >> 4) * 4;

  if (SIM) {
    // bias + relu in place
#pragma unroll
    for (int ni = 0; ni < 4; ++ni) {
      const float bv_ = bias[tn * 128 + wn * 64 + ni * 16 + rl];
#pragma unroll
      for (int mi = 0; mi < 4; ++mi)
#pragma unroll
        for (int r = 0; r < 4; ++r)
          acc[mi][ni][r] = fmaxf(acc[mi][ni][r] + bv_, 0.f);
    }
    // partial sim: s[m] = sum_ni v * memS[m][lcol(ni)], reduce over 16-lane rl group
#pragma unroll
    for (int mi = 0; mi < 4; ++mi) {
#pragma unroll
      for (int r = 0; r < 4; ++r) {
        float s[8];
#pragma unroll
        for (int m = 0; m < 8; ++m) s[m] = 0.f;
#pragma unroll
        for (int ni = 0; ni < 4; ++ni) {
          const float v = acc[mi][ni][r];
          const int lc = wn * 64 + ni * 16 + rl;
#pragma unroll
          for (int m = 0; m < 8; ++m) s[m] = fmaf(v, memS[m * 128 + lc], s[m]);
        }
#pragma unroll
        for (int off = 1; off < 16; off <<= 1)
#pragma unroll
          for (int m = 0; m < 8; ++m) s[m] += __shfl_xor(s[m], off, 64);
        const int row = tm * 128 + wm * 64 + mi * 16 + rg + r;
        if (rl < 8 && row < N_NODES) {
          float val = 0.f;
#pragma unroll
          for (int m = 0; m < 8; ++m) val = (rl == m) ? s[m] : val;
          atomicAdd(&simraw[(size_t)row * 8 + rl], val);
        }
      }
    }
    return;
  }

  // epilogue: bias (+ relu) -> bf16 (and optionally fp8 via LDS repack)
  __bf16* rep = (__bf16*)smem;    // [128][132] bf16 = 33792B; ring dead after loop
  if (H8) __syncthreads();        // all waves done with ring LDS before overwrite
#pragma unroll
  for (int ni = 0; ni < 4; ++ni) {
    const int lcol = wn * 64 + ni * 16 + rl;
    const int col = tn * 128 + lcol;
    const float bv_ = bias[col];
#pragma unroll
    for (int mi = 0; mi < 4; ++mi) {
      const int lrowb = wm * 64 + mi * 16 + rg;
      const int rowb = tm * 128 + lrowb;
#pragma unroll
      for (int r = 0; r < 4; ++r) {
        float v = acc[mi][ni][r] + bv_;
        if (RELU) v = fmaxf(v, 0.f);
        const __bf16 bvv = (__bf16)v;
        C[(size_t)(rowb + r) * NH + col] = bvv;
        if (H8) rep[(lrowb + r) * 132 + lcol] = bvv;
      }
    }
  }
  if (H8) {
    __syncthreads();
    const int lrow = tid >> 1;
    const int row_g = tm * 128 + lrow;
    if (row_g < N_NODES) {
      const __bf16* srcp = rep + lrow * 132 + (tid & 1) * 64;
      unsigned dw[16];
#pragma unroll
      for (int q = 0; q < 16; ++q) {
        int w = 0;
        w = __builtin_amdgcn_cvt_pk_fp8_f32((float)srcp[q*4+0], (float)srcp[q*4+1], w, false);
        w = __builtin_amdgcn_cvt_pk_fp8_f32((float)srcp[q*4+2], (float)srcp[q*4+3], w, true);
        dw[q] = (unsigned)w;
      }
      unsigned* dstp = C8 + (size_t)row_g * 128 + (tn * 128 + (tid & 1) * 64) / 4;
#pragma unroll
      for (int q = 0; q < 4; ++q)
        *(uint4*)(dstp + q * 4) = uint4{dw[q*4], dw[q*4+1], dw[q*4+2], dw[q*4+3]};
    }
  }
}

// ---------------- smpool: softmax(simraw) -> (sim0?) + pooling of sim@mem ----------------
template<bool WRITE_SIM>
__global__ __launch_bounds__(256) void smpool_kernel(const float* __restrict__ simraw,
                                                     const float* __restrict__ mem,
                                                     const int* __restrict__ batch,
                                                     unsigned* __restrict__ gmax,
                                                     float* __restrict__ gsum,
                                                     int colofs,
                                                     float* __restrict__ simout) {
  __shared__ float sm[8 * 512];
  const int tid = threadIdx.x;
  for (int i = tid; i < 4096; i += 256) sm[i] = mem[i];
  __syncthreads();
  const int lane = tid & 63;
  const int n0 = blockIdx.x * 128 + (tid >> 6) * 32;
  const int nend = min(n0 + 32, N_NODES);

  float mx[8], sv[8];
#pragma unroll
  for (int j = 0; j < 8; ++j) { mx[j] = -3.0e38f; sv[j] = 0.f; }
  int cur = -1;

  for (int n = n0; n < nend; ++n) {
    const int g = batch[n];
    if (g != cur) {
      if (cur >= 0) {
#pragma unroll
        for (int j = 0; j < 8; ++j) {
          atomicMax(&gmax[(size_t)cur * 1024 + colofs + lane + j * 64], enc_f32(mx[j]));
          atomicAdd(&gsum[(size_t)cur * 1024 + colofs + lane + j * 64], sv[j]);
        }
      }
      cur = g;
#pragma unroll
      for (int j = 0; j < 8; ++j) { mx[j] = -3.0e38f; sv[j] = 0.f; }
    }
    f32x4 r0 = *(const f32x4*)(simraw + (size_t)n * 8);
    f32x4 r1 = *(const f32x4*)(simraw + (size_t)n * 8 + 4);
    float w[8] = {r0[0],r0[1],r0[2],r0[3],r1[0],r1[1],r1[2],r1[3]};
    float smx = w[0];
#pragma unroll
    for (int m = 1; m < 8; ++m) smx = fmaxf(smx, w[m]);
    float ssum = 0.f;
#pragma unroll
    for (int m = 0; m < 8; ++m) { w[m] = __expf(w[m] - smx); ssum += w[m]; }
    const float inv = 1.f / ssum;
#pragma unroll
    for (int m = 0; m < 8; ++m) w[m] *= inv;
    if (WRITE_SIM && lane == 0) {
      f32x4 o0{w[0], w[1], w[2], w[3]};
      f32x4 o1{w[4], w[5], w[6], w[7]};
      *(f32x4*)(simout + (size_t)n * 8) = o0;
      *(f32x4*)(simout + (size_t)n * 8 + 4) = o1;
    }
    float outv[8] = {0.f,0.f,0.f,0.f,0.f,0.f,0.f,0.f};
#pragma unroll
    for (int m = 0; m < 8; ++m) {
      const float wm_ = w[m];
      const float* mr = sm + m * 512 + lane;
#pragma unroll
      for (int j = 0; j < 8; ++j) outv[j] += wm_ * mr[j * 64];
    }
#pragma unroll
    for (int j = 0; j < 8; ++j) {
      mx[j] = fmaxf(mx[j], outv[j]);
      sv[j] += outv[j];
    }
  }
  if (cur >= 0) {
#pragma unroll
    for (int j = 0; j < 8; ++j) {
      atomicMax(&gmax[(size_t)cur * 1024 + colofs + lane + j * 64], enc_f32(mx[j]));
      atomicAdd(&gsum[(size_t)cur * 1024 + colofs + lane + j * 64], sv[j]);
    }
  }
}

// ---------------- graph ranges (batch is sorted) ----------------
__global__ __launch_bounds__(256) void ranges_kernel(const int* __restrict__ batch,
                                                     int* __restrict__ gstart) {
  int g = blockIdx.x * 256 + threadIdx.x;
  if (g > N_GRAPH) return;
  if (g == N_GRAPH) { gstart[N_GRAPH] = N_NODES; return; }
  int lo = 0, hi = N_NODES;
  while (lo < hi) {
    int mid = (lo + hi) >> 1;
    if (batch[mid] < g) lo = mid + 1; else hi = mid;
  }
  gstart[g] = lo;
}

// ---------------- pooling decode: gf [G][2048] = [max | mean] ----------------
__global__ __launch_bounds__(256) void pool2_kernel(const unsigned* __restrict__ gmax,
                                                    const float* __restrict__ gsum,
                                                    const int* __restrict__ gstart,
                                                    float* __restrict__ g) {
  const int gr = blockIdx.x;
  const int t = threadIdx.x;
  const int cnt = gstart[gr + 1] - gstart[gr];
  const float inv = 1.f / fmaxf((float)cnt, 1.f);
#pragma unroll
  for (int j = 0; j < 4; ++j) {
    const int f = t * 4 + j;
    unsigned u = gmax[(size_t)gr * 1024 + f];
    g[(size_t)gr * 2048 + f] = (cnt > 0) ? dec_f32(u) : 0.f;
    g[(size_t)gr * 2048 + 1024 + f] = gsum[(size_t)gr * 1024 + f] * inv;
  }
}

// ---------------- classifier head: log_softmax(g @ lin_w + lin_b) ----------------
__global__ __launch_bounds__(64) void classify_kernel(const float* __restrict__ g,
                                                      const float* __restrict__ lw,
                                                      const float* __restrict__ lb,
                                                      float* __restrict__ out) {
  const int gr = blockIdx.x;
  const int lane = threadIdx.x;   // 64
  float acc[10];
  for (int c = 0; c < 10; ++c) acc[c] = 0.f;
  const float* grow = g + (size_t)gr * 2048;
  for (int k = lane; k < 2048; k += 64) {
    float gv = grow[k];
    const float* w = lw + (size_t)k * 10;
#pragma unroll
    for (int c = 0; c < 10; ++c) acc[c] += gv * w[c];
  }
  for (int c = 0; c < 10; ++c)
    for (int off = 32; off; off >>= 1) acc[c] += __shfl_xor(acc[c], off, 64);
  if (lane == 0) {
    float lg[10];
    float mx = -3.0e38f;
    for (int c = 0; c < 10; ++c) { lg[c] = acc[c] + lb[c]; mx = fmaxf(mx, lg[c]); }
    float s = 0.f;
    for (int c = 0; c < 10; ++c) s += expf(lg[c] - mx);
    float lse = logf(s);
    for (int c = 0; c < 10; ++c) out[(size_t)gr * 10 + c] = lg[c] - mx - lse;
  }
}

// =======================================================================================
extern "C" void kernel_launch(void* const* d_in, const int* in_sizes, int n_in,
                              void* d_out, int out_size, void* d_ws, size_t ws_size,
                              hipStream_t stream) {
  (void)in_sizes; (void)n_in; (void)out_size; (void)ws_size;
  const float* x      = (const float*)d_in[0];
  const int*   eidx   = (const int*)d_in[1];
  const int*   batch  = (const int*)d_in[2];
  const float* pre_w  = (const float*)d_in[4];
  const float* pre_b  = (const float*)d_in[5];
  const float* w1_0   = (const float*)d_in[6];
  const float* b1_0   = (const float*)d_in[7];
  const float* w2_0   = (const float*)d_in[8];
  const float* b2_0   = (const float*)d_in[9];
  const float* mem_0  = (const float*)d_in[10];
  const float* w1_1   = (const float*)d_in[11];
  const float* b1_1   = (const float*)d_in[12];
  const float* w2_1   = (const float*)d_in[13];
  const float* b2_1   = (const float*)d_in[14];
  const float* mem_1  = (const float*)d_in[15];
  const float* lin_w  = (const float*)d_in[16];
  const float* lin_b  = (const float*)d_in[17];
  float* out = (float*)d_out;

  const int* src = eidx;
  const int* dst = eidx + N_EDGES;

  // ---- workspace carve ----
  char* p = (char*)d_ws;
  auto alloc = [&](size_t bytes) -> char* {
    char* r = p;
    p += (bytes + 255) & ~(size_t)255;
    return r;
  };
  __bf16* xb    = (__bf16*)alloc((size_t)MP * 512 * 2);
  __bf16* hb    = (__bf16*)alloc((size_t)MP * 512 * 2);
  __bf16* aggb  = (__bf16*)alloc((size_t)MP * 512 * 2);
  __bf16* y1b   = (__bf16*)alloc((size_t)MP * 512 * 2);
  unsigned* h8  = (unsigned*)alloc((size_t)N_NODES * 512);
  __bf16* preT  = (__bf16*)alloc((size_t)512 * 512 * 2);
  __bf16* w1T0  = (__bf16*)alloc((size_t)512 * 1024 * 2);
  __bf16* w2T0  = (__bf16*)alloc((size_t)512 * 512 * 2);
  __bf16* w2T1  = (__bf16*)alloc((size_t)512 * 512 * 2);
  int* deg      = (int*)alloc((size_t)N_NODES * 4);
  int* rowstart = (int*)alloc((size_t)(N_NODES + 1) * 4);
  int* cursor   = (int*)alloc((size_t)N_NODES * 4);
  int* bsum     = (int*)alloc(128 * 4);
  int* csr      = (int*)alloc((size_t)N_EDGES * 4);
  int* gstart   = (int*)alloc((size_t)(N_GRAPH + 1) * 4);
  float* gf     = (float*)alloc((size_t)N_GRAPH * 2048 * 4);
  unsigned* gmax = (unsigned*)alloc((size_t)N_GRAPH * 1024 * 4);
  float* gsum    = (float*)alloc((size_t)N_GRAPH * 1024 * 4);
  float* sim0    = (float*)alloc((size_t)N_NODES * 8 * 4);
  float* simraw  = (float*)alloc((size_t)N_NODES * 8 * 4);
  float* aggS    = (float*)alloc((size_t)N_NODES * 8 * 4);
  float* UV      = (float*)alloc((size_t)16 * 512 * 4);

  // ---- dynamic LDS: 64KB ring (+4KB mem slice for SIM) ----
  const int GEMM_LDS = 69632;
  hipFuncSetAttribute(reinterpret_cast<const void*>(&gemm128_kernel<512,  false, false, true,  false>),
                      hipFuncAttributeMaxDynamicSharedMemorySize, GEMM_LDS);
  hipFuncSetAttribute(reinterpret_cast<const void*>(&gemm128_kernel<1024, true,  true,  false, false>),
                      hipFuncAttributeMaxDynamicSharedMemorySize, GEMM_LDS);
  hipFuncSetAttribute(reinterpret_cast<const void*>(&gemm128_kernel<512,  false, true,  false, true>),
                      hipFuncAttributeMaxDynamicSharedMemorySize, GEMM_LDS);

  // ---- weight prep ----
  transpose_kernel<<<dim3(16, 16), 256, 0, stream>>>(pre_w, preT, 512, 512);
  transpose_kernel<<<dim3(16, 32), 256, 0, stream>>>(w1_0, w1T0, 1024, 512);
  transpose_kernel<<<dim3(16, 16), 256, 0, stream>>>(w2_0, w2T0, 512, 512);
  transpose_kernel<<<dim3(16, 16), 256, 0, stream>>>(w2_1, w2T1, 512, 512);
  uv_kernel<<<16, 512, 0, stream>>>(mem_0, w1_1, UV);   // rank-8 tables for layer 1

  // ---- input cast ----
  castx_kernel<<<25024, 256, 0, stream>>>(x, xb);

  // ---- CSR build (per call; deterministic work) ----
  hipMemsetAsync(deg, 0, (size_t)N_NODES * 4, stream);
  degree_kernel<<<3125, 256, 0, stream>>>(dst, deg);
  scan1_kernel<<<98, 256, 0, stream>>>(deg, rowstart, bsum, N_NODES);
  scan2_kernel<<<1, 64, 0, stream>>>(bsum, 98);
  scan3_kernel<<<392, 256, 0, stream>>>(rowstart, bsum, cursor, N_NODES);
  scatter_kernel<<<3125, 256, 0, stream>>>(src, dst, cursor, csr);

  // pooling accumulators: gmax||gsum contiguous -> one memset; sim0||simraw too
  hipMemsetAsync(gmax, 0, (size_t)N_GRAPH * 1024 * 4 * 2, stream);
  ranges_kernel<<<2, 256, 0, stream>>>(batch, gstart);

  const int GG = 1564;   // 391 M-tiles x 4 N-tiles

  // ---- pre conv: h = x @ pre_w + pre_b (emits bf16 + fp8 copies) ----
  gemm128_kernel<512, false, false, true, false><<<GG, 256, GEMM_LDS, stream>>>(
      xb, nullptr, preT, pre_b, hb, h8, nullptr, nullptr);

  // ---- layer 0 ----
  aggregate8_kernel<<<25000, 256, 0, stream>>>(h8, rowstart, csr, aggb);
  gemm128_kernel<1024, true, true, false, false><<<GG, 256, GEMM_LDS, stream>>>(
      hb, aggb, w1T0, b1_0, y1b, nullptr, nullptr, nullptr);
  hipMemsetAsync(simraw, 0, (size_t)N_NODES * 8 * 4, stream);
  gemm128_kernel<512, false, true, false, true><<<GG, 256, GEMM_LDS, stream>>>(
      y1b, nullptr, w2T0, b2_0, nullptr, nullptr, mem_0, simraw);
  smpool_kernel<true><<<782, 256, 0, stream>>>(simraw, mem_0, batch, gmax, gsum, 0, sim0);

  // ---- layer 1 (rank-8 collapsed front half) ----
  aggsim_kernel<<<391, 256, 0, stream>>>(sim0, rowstart, csr, aggS);
  z1y_kernel<<<25000, 256, 0, stream>>>(sim0, aggS, UV, b1_1, y1b);
  hipMemsetAsync(simraw, 0, (size_t)N_NODES * 8 * 4, stream);
  gemm128_kernel<512, false, true, false, true><<<GG, 256, GEMM_LDS, stream>>>(
      y1b, nullptr, w2T1, b2_1, nullptr, nullptr, mem_1, simraw);
  smpool_kernel<false><<<782, 256, 0, stream>>>(simraw, mem_1, batch, gmax, gsum, 512, nullptr);

  // ---- readout ----
  pool2_kernel<<<N_GRAPH, 256, 0, stream>>>(gmax, gsum, gstart, gf);
  classify_kernel<<<N_GRAPH, 64, 0, stream>>>(gf, lin_w, lin_b, out);
}

// Round 17
// 746.166 us; speedup vs baseline: 1.0246x; 1.0246x over previous
//
#include <hip/hip_runtime.h>

#define N_NODES 100000
#define N_EDGES 800000
#define N_GRAPH 256
#define MP      100096   // 391 * 256, padded M
#define NH      512
#define SLICE   ((size_t)N_NODES * 8)

typedef __bf16 bf16x4v __attribute__((ext_vector_type(4)));
typedef __bf16 bf16x8v __attribute__((ext_vector_type(8)));
typedef float  f32x4   __attribute__((ext_vector_type(4)));
typedef float  f32x2   __attribute__((ext_vector_type(2)));

__device__ __forceinline__ void gload_lds16(const void* g, void* l) {
  __builtin_amdgcn_global_load_lds((const __attribute__((address_space(1))) void*)g,
                                   (__attribute__((address_space(3))) void*)l, 16, 0, 0);
}

// order-preserving fp32 <-> uint32 encoding for atomicMax
__device__ __forceinline__ unsigned enc_f32(float f) {
  unsigned u = __float_as_uint(f);
  return (u & 0x80000000u) ? ~u : (u | 0x80000000u);
}
__device__ __forceinline__ float dec_f32(unsigned u) {
  return (u & 0x80000000u) ? __uint_as_float(u & 0x7FFFFFFFu) : __uint_as_float(~u);
}

// ---------------- cast x (fp32) -> padded bf16 [MP][512] ----------------
__global__ __launch_bounds__(256) void castx_kernel(const float* __restrict__ x,
                                                    __bf16* __restrict__ xb) {
  const size_t i = (size_t)blockIdx.x * 256 + threadIdx.x;   // 8-elem chunk id
  const size_t row = i >> 6;
  const int c = (int)(i & 63) * 8;
  if (row >= MP) return;
  bf16x8v o;
  if (row < N_NODES) {
    const float* p = x + row * 512 + c;
    f32x4 a = *(const f32x4*)p;
    f32x4 b = *(const f32x4*)(p + 4);
    o[0]=(__bf16)a[0]; o[1]=(__bf16)a[1]; o[2]=(__bf16)a[2]; o[3]=(__bf16)a[3];
    o[4]=(__bf16)b[0]; o[5]=(__bf16)b[1]; o[6]=(__bf16)b[2]; o[7]=(__bf16)b[3];
  } else {
    for (int j = 0; j < 8; ++j) o[j] = (__bf16)0.0f;
  }
  *(bf16x8v*)(xb + row * 512 + c) = o;
}

// ---------------- weight transpose: W[K][N] fp32 -> BT[N][K] bf16 ----------------
__global__ __launch_bounds__(256) void transpose_kernel(const float* __restrict__ W,
                                                        __bf16* __restrict__ BT,
                                                        int K, int Nn) {
  __shared__ float tile[32][33];
  const int bx = blockIdx.x;   // n tile
  const int by = blockIdx.y;   // k tile
  const int tx = threadIdx.x & 31;
  const int ty = threadIdx.x >> 5;   // 0..7
  for (int j = 0; j < 4; ++j) {
    int k = by * 32 + ty + j * 8;
    int n = bx * 32 + tx;
    tile[ty + j * 8][tx] = W[(size_t)k * Nn + n];
  }
  __syncthreads();
  for (int j = 0; j < 4; ++j) {
    int n = bx * 32 + ty + j * 8;
    int k = by * 32 + tx;
    BT[(size_t)n * K + k] = (__bf16)tile[tx][ty + j * 8];
  }
}

// ---------------- CSR build ----------------
__global__ __launch_bounds__(256) void degree_kernel(const int* __restrict__ dst,
                                                     int* __restrict__ deg) {
  int e = blockIdx.x * 256 + threadIdx.x;
  if (e < N_EDGES) atomicAdd(&deg[dst[e]], 1);
}

__global__ __launch_bounds__(256) void scan1_kernel(const int* __restrict__ deg,
                                                    int* __restrict__ rs,
                                                    int* __restrict__ bsum, int n) {
  __shared__ int lds[256];
  const int b = blockIdx.x, t = threadIdx.x;
  const int base = b * 1024 + t * 4;
  int v[4];
  for (int j = 0; j < 4; ++j) v[j] = (base + j < n) ? deg[base + j] : 0;
  int tsum = v[0] + v[1] + v[2] + v[3];
  lds[t] = tsum;
  __syncthreads();
  for (int off = 1; off < 256; off <<= 1) {
    int x = 0;
    if (t >= off) x = lds[t - off];
    __syncthreads();
    lds[t] += x;
    __syncthreads();
  }
  int run = lds[t] - tsum;   // exclusive prefix of this thread
  for (int j = 0; j < 4; ++j) {
    if (base + j < n) rs[base + j] = run;
    run += v[j];
  }
  if (t == 255) bsum[b] = lds[255];
}

__global__ void scan2_kernel(int* bsum, int nb) {
  if (threadIdx.x == 0 && blockIdx.x == 0) {
    int run = 0;
    for (int i = 0; i < nb; ++i) { int v = bsum[i]; bsum[i] = run; run += v; }
  }
}

__global__ __launch_bounds__(256) void scan3_kernel(int* __restrict__ rs,
                                                    const int* __restrict__ bsum,
                                                    int* __restrict__ cursor, int n) {
  int i = blockIdx.x * 256 + threadIdx.x;
  if (i < n) {
    int v = rs[i] + bsum[i >> 10];
    rs[i] = v;
    cursor[i] = v;
  } else if (i == n) {
    rs[n] = N_EDGES;
  }
}

__global__ __launch_bounds__(256) void scatter_kernel(const int* __restrict__ src,
                                                      const int* __restrict__ dst,
                                                      int* __restrict__ cursor,
                                                      int* __restrict__ csr) {
  int e = blockIdx.x * 256 + threadIdx.x;
  if (e < N_EDGES) {
    int slot = atomicAdd(&cursor[dst[e]], 1);
    csr[slot] = src[e];
  }
}

// ---------------- aggregate (fp8 gather): agg[n] = sum_{e: dst==n} h8[src[e]] ------------
__global__ __launch_bounds__(256) void aggregate8_kernel(const unsigned* __restrict__ h8,
                                                         const int* __restrict__ rs,
                                                         const int* __restrict__ csr,
                                                         __bf16* __restrict__ agg) {
  const int node = blockIdx.x * 4 + (threadIdx.x >> 6);
  if (node >= N_NODES) return;
  const int lane = threadIdx.x & 63;
  const int s = rs[node], e = rs[node + 1];
  float acc[8] = {0.f,0.f,0.f,0.f,0.f,0.f,0.f,0.f};
  const size_t lofs = (size_t)lane * 2;     // 8 fp8 = 2 dwords per lane
  for (int i = s; i < e; i += 4) {
    const int i1 = (i + 1 < e) ? i + 1 : i;
    const int i2 = (i + 2 < e) ? i + 2 : i;
    const int i3 = (i + 3 < e) ? i + 3 : i;
    const float w1 = (i + 1 < e) ? 1.f : 0.f;
    const float w2 = (i + 2 < e) ? 1.f : 0.f;
    const float w3 = (i + 3 < e) ? 1.f : 0.f;
    const int n0 = csr[i], n1 = csr[i1], n2 = csr[i2], n3 = csr[i3];
    uint2 u0 = *(const uint2*)(h8 + (size_t)n0 * 128 + lofs);
    uint2 u1 = *(const uint2*)(h8 + (size_t)n1 * 128 + lofs);
    uint2 u2 = *(const uint2*)(h8 + (size_t)n2 * 128 + lofs);
    uint2 u3 = *(const uint2*)(h8 + (size_t)n3 * 128 + lofs);

    f32x2 a, b, c, d;
    a = __builtin_amdgcn_cvt_pk_f32_fp8((int)u0.x, false);
    b = __builtin_amdgcn_cvt_pk_f32_fp8((int)u0.x, true);
    c = __builtin_amdgcn_cvt_pk_f32_fp8((int)u0.y, false);
    d = __builtin_amdgcn_cvt_pk_f32_fp8((int)u0.y, true);
    acc[0]+=a[0]; acc[1]+=a[1]; acc[2]+=b[0]; acc[3]+=b[1];
    acc[4]+=c[0]; acc[5]+=c[1]; acc[6]+=d[0]; acc[7]+=d[1];

    a = __builtin_amdgcn_cvt_pk_f32_fp8((int)u1.x, false);
    b = __builtin_amdgcn_cvt_pk_f32_fp8((int)u1.x, true);
    c = __builtin_amdgcn_cvt_pk_f32_fp8((int)u1.y, false);
    d = __builtin_amdgcn_cvt_pk_f32_fp8((int)u1.y, true);
    acc[0]=fmaf(w1,a[0],acc[0]); acc[1]=fmaf(w1,a[1],acc[1]);
    acc[2]=fmaf(w1,b[0],acc[2]); acc[3]=fmaf(w1,b[1],acc[3]);
    acc[4]=fmaf(w1,c[0],acc[4]); acc[5]=fmaf(w1,c[1],acc[5]);
    acc[6]=fmaf(w1,d[0],acc[6]); acc[7]=fmaf(w1,d[1],acc[7]);

    a = __builtin_amdgcn_cvt_pk_f32_fp8((int)u2.x, false);
    b = __builtin_amdgcn_cvt_pk_f32_fp8((int)u2.x, true);
    c = __builtin_amdgcn_cvt_pk_f32_fp8((int)u2.y, false);
    d = __builtin_amdgcn_cvt_pk_f32_fp8((int)u2.y, true);
    acc[0]=fmaf(w2,a[0],acc[0]); acc[1]=fmaf(w2,a[1],acc[1]);
    acc[2]=fmaf(w2,b[0],acc[2]); acc[3]=fmaf(w2,b[1],acc[3]);
    acc[4]=fmaf(w2,c[0],acc[4]); acc[5]=fmaf(w2,c[1],acc[5]);
    acc[6]=fmaf(w2,d[0],acc[6]); acc[7]=fmaf(w2,d[1],acc[7]);

    a = __builtin_amdgcn_cvt_pk_f32_fp8((int)u3.x, false);
    b = __builtin_amdgcn_cvt_pk_f32_fp8((int)u3.x, true);
    c = __builtin_amdgcn_cvt_pk_f32_fp8((int)u3.y, false);
    d = __builtin_amdgcn_cvt_pk_f32_fp8((int)u3.y, true);
    acc[0]=fmaf(w3,a[0],acc[0]); acc[1]=fmaf(w3,a[1],acc[1]);
    acc[2]=fmaf(w3,b[0],acc[2]); acc[3]=fmaf(w3,b[1],acc[3]);
    acc[4]=fmaf(w3,c[0],acc[4]); acc[5]=fmaf(w3,c[1],acc[5]);
    acc[6]=fmaf(w3,d[0],acc[6]); acc[7]=fmaf(w3,d[1],acc[7]);
  }
  bf16x8v o;
#pragma unroll
  for (int j = 0; j < 8; ++j) o[j] = (__bf16)acc[j];
  *(bf16x8v*)(agg + (size_t)node * 512 + (size_t)lane * 8) = o;
}

// ---------------- aggregate (layer 1, rank-8): aggS[n] = sum sim0[src] ----------------
__global__ __launch_bounds__(256) void aggsim_kernel(const float* __restrict__ sim,
                                                     const int* __restrict__ rs,
                                                     const int* __restrict__ csr,
                                                     float* __restrict__ aggS) {
  const int node = blockIdx.x * 256 + threadIdx.x;
  if (node >= N_NODES) return;
  f32x4 a0 = f32x4{0.f,0.f,0.f,0.f}, a1 = f32x4{0.f,0.f,0.f,0.f};
  const int s = rs[node], e = rs[node + 1];
  for (int i = s; i < e; ++i) {
    const int sn = csr[i];
    a0 += *(const f32x4*)(sim + (size_t)sn * 8);
    a1 += *(const f32x4*)(sim + (size_t)sn * 8 + 4);
  }
  *(f32x4*)(aggS + (size_t)node * 8) = a0;
  *(f32x4*)(aggS + (size_t)node * 8 + 4) = a1;
}

// ---------------- UV: U[m] = mem0[m] @ W1_1[0:512], V[m] = mem0[m] @ W1_1[512:1024] -----
__global__ __launch_bounds__(512) void uv_kernel(const float* __restrict__ mem,
                                                 const float* __restrict__ w1,
                                                 float* __restrict__ UV) {
  const int mu = blockIdx.x;        // 0..15
  const int c  = threadIdx.x;       // 0..511
  const int m = mu & 7, half = mu >> 3;
  const float* wbase = w1 + (size_t)(half * 512) * 512;
  const float* mrow  = mem + (size_t)m * 512;
  float acc = 0.f;
  for (int k = 0; k < 512; ++k) acc += mrow[k] * wbase[(size_t)k * 512 + c];
  UV[(size_t)mu * 512 + c] = acc;
}

// ---------------- z1y: y1 = relu(sim0 @ U + aggS @ V + b1), [N,512] bf16 ----------------
__global__ __launch_bounds__(256) void z1y_kernel(const float* __restrict__ sim,
                                                  const float* __restrict__ aggS,
                                                  const float* __restrict__ UV,
                                                  const float* __restrict__ b1,
                                                  __bf16* __restrict__ y) {
  __shared__ float suv[16 * 512];   // 32KB
  __shared__ float sb[512];
  const int tid = threadIdx.x;
  for (int i = tid; i < 8192; i += 256) suv[i] = UV[i];
  for (int i = tid; i < 512; i += 256) sb[i] = b1[i];
  __syncthreads();
  const int node = blockIdx.x * 4 + (tid >> 6);
  if (node >= N_NODES) return;
  const int lane = tid & 63;
  f32x4 s0 = *(const f32x4*)(sim + (size_t)node * 8);
  f32x4 s1 = *(const f32x4*)(sim + (size_t)node * 8 + 4);
  f32x4 a0 = *(const f32x4*)(aggS + (size_t)node * 8);
  f32x4 a1 = *(const f32x4*)(aggS + (size_t)node * 8 + 4);
  float sv[8] = {s0[0],s0[1],s0[2],s0[3],s1[0],s1[1],s1[2],s1[3]};
  float av[8] = {a0[0],a0[1],a0[2],a0[3],a1[0],a1[1],a1[2],a1[3]};
  __bf16* yrow = y + (size_t)node * 512;
#pragma unroll
  for (int j = 0; j < 8; ++j) {
    const int c = lane + j * 64;
    float acc = sb[c];
#pragma unroll
    for (int m = 0; m < 8; ++m) {
      acc += sv[m] * suv[m * 512 + c];
      acc += av[m] * suv[(8 + m) * 512 + c];
    }
    yrow[c] = (__bf16)fmaxf(acc, 0.f);
  }
}

// ---------------- GEMM 128x128, BK=32, ring-4 depth-3, 64KB LDS -> 2 blocks/CU ----------
// C[M][512] = relu?( A @ BT^T + bias ), bf16 in/out, fp32 acc.
// H8:  epilogue additionally emits fp8-e4m3 copy of C (LDS repack; ring dead post-loop).
// SIM: epilogue does NOT write C; repacks relu(z) tile to LDS, then ONE THREAD-PAIR PER
//      ROW computes s[m] = sum_col v*memS[m][col] (512 fmaf, only 8 shuffles) and stores
//      non-atomically into per-tn slice simraw4[tn][row][8] (summed later in smpool).
template<int KTOT, bool SPLIT, bool RELU, bool H8, bool SIM>
__global__ __launch_bounds__(256, 2) void gemm128_kernel(const __bf16* __restrict__ A1,
                                                         const __bf16* __restrict__ A2,
                                                         const __bf16* __restrict__ BT,
                                                         const float* __restrict__ bias,
                                                         __bf16* __restrict__ C,
                                                         unsigned* __restrict__ C8,
                                                         const float* __restrict__ memf,
                                                         float* __restrict__ simraw4) {
  extern __shared__ char smem[];
  __bf16* As = (__bf16*)smem;              // 4 slots * 8KB = 32KB
  __bf16* Bs = (__bf16*)(smem + 32768);    // 32KB
  float* memS = (float*)(smem + 65536);    // [8][128] fp32 (SIM only)
  const int tid  = threadIdx.x;
  const int wid  = tid >> 6;     // 0..3
  const int lane = tid & 63;
  const int wm = wid >> 1;       // 0..1
  const int wn = wid & 1;        // 0..1
  const int srow = tid >> 2;     // 0..63 (row within 64-row half)
  const int scol = ((tid & 3) ^ ((tid >> 3) & 3)) * 8;   // inverse-swizzled source chunk
  const int rl  = lane & 15;
  const int rdk = (((lane >> 4) ^ ((lane >> 1) & 3)) * 8);  // swizzled read chunk

  // XCD-aware bijective remap (1564 = 4*196 + 4*195); the 4 N-tiles of a tm share an XCD
  const int bid = blockIdx.x;
  const int xcd = bid & 7, pos = bid >> 3;
  const int idx = (xcd < 4) ? (xcd * 196 + pos) : (784 + (xcd - 4) * 195 + pos);
  const int tm = idx >> 2, tn = idx & 3;

  constexpr int NT = KTOT / 32;

  // SIM: stage this block's mem slice [8][tn*128 .. +128]; visibility guarded by the
  // epilogue __syncthreads before any cross-thread read.
  if (SIM) {
    const int m = tid >> 5, c4 = (tid & 31) * 4;
    f32x4 v = *(const f32x4*)(memf + (size_t)m * 512 + tn * 128 + c4);
    *(f32x4*)(memS + m * 128 + c4) = v;
  }

  f32x4 acc[4][4];
#pragma unroll
  for (int mi = 0; mi < 4; ++mi)
#pragma unroll
    for (int ni = 0; ni < 4; ++ni)
      acc[mi][ni] = f32x4{0.f, 0.f, 0.f, 0.f};

  auto stage = [&](int tk) {
    const int slot = tk & 3;
    const __bf16* Ap = A1;
    int kc = tk * 32;
    if (SPLIT && tk >= NT / 2) { Ap = A2; kc -= 512; }
#pragma unroll
    for (int j = 0; j < 2; ++j) {
      const __bf16* g = Ap + (size_t)(tm * 128 + j * 64 + srow) * NH + (kc + scol);
      gload_lds16(g, (char*)As + slot * 8192 + j * 4096 + wid * 1024);
    }
#pragma unroll
    for (int j = 0; j < 2; ++j) {
      const __bf16* g = BT + (size_t)(tn * 128 + j * 64 + srow) * KTOT + (tk * 32 + scol);
      gload_lds16(g, (char*)Bs + slot * 8192 + j * 4096 + wid * 1024);
    }
  };

  // prologue: fill 3 slots (12 loads in flight)
  stage(0); stage(1); stage(2);

  for (int tk = 0; tk < NT; ++tk) {
    if (tk < NT - 2)       asm volatile("s_waitcnt vmcnt(8)" ::: "memory");
    else if (tk == NT - 2) asm volatile("s_waitcnt vmcnt(4)" ::: "memory");
    else                   asm volatile("s_waitcnt vmcnt(0)" ::: "memory");
    __builtin_amdgcn_s_barrier();            // tile tk landed, tile tk-1 consumed
    asm volatile("" ::: "memory");           // pin LDS ops after the barrier

    if (tk + 3 < NT) stage(tk + 3);          // overwrites slot (tk-1)&3 -- safe post-barrier

    const int slot = tk & 3;
    const __bf16* a0 = As + slot * 4096 + (wm * 64 + rl) * 32 + rdk;
    const __bf16* b0 = Bs + slot * 4096 + (wn * 64 + rl) * 32 + rdk;
    bf16x8v av[4], bv[4];
#pragma unroll
    for (int mi = 0; mi < 4; ++mi) av[mi] = *(const bf16x8v*)(a0 + mi * 16 * 32);
#pragma unroll
    for (int ni = 0; ni < 4; ++ni) bv[ni] = *(const bf16x8v*)(b0 + ni * 16 * 32);

    __builtin_amdgcn_s_setprio(1);
#pragma unroll
    for (int mi = 0; mi < 4; ++mi)
#pragma unroll
      for (int ni = 0; ni < 4; ++ni)
        acc[mi][ni] = __builtin_amdgcn_mfma_f32_16x16x32_bf16(av[mi], bv[ni], acc[mi][ni], 0, 0, 0);
    __builtin_amdgcn_s_setprio(0);
  }

  const int rg = (lane >> 4) * 4;
  __bf16* rep = (__bf16*)smem;    // [128][132] bf16 = 33792B; ring dead after loop

  if (SIM) {
    __syncthreads();              // ring reads done; memS writes published
    // bias + relu -> rep
#pragma unroll
    for (int ni = 0; ni < 4; ++ni) {
      const int lcol = wn * 64 + ni * 16 + rl;
      const float bv_ = bias[tn * 128 + lcol];
#pragma unroll
      for (int mi = 0; mi < 4; ++mi) {
        const int lrowb = wm * 64 + mi * 16 + rg;
#pragma unroll
        for (int r = 0; r < 4; ++r)
          rep[(lrowb + r) * 132 + lcol] = (__bf16)fmaxf(acc[mi][ni][r] + bv_, 0.f);
      }
    }
    __syncthreads();
    // one thread-pair per row: s[m] = sum over this half's 64 cols
    const int lrow = tid >> 1, half = tid & 1;
    const int grow = tm * 128 + lrow;
    float s[8] = {0.f,0.f,0.f,0.f,0.f,0.f,0.f,0.f};
    const __bf16* rp = rep + lrow * 132 + half * 64;
    const float* ms = memS + half * 64;
#pragma unroll
    for (int c8 = 0; c8 < 8; ++c8) {
      bf16x8v v = *(const bf16x8v*)(rp + c8 * 8);
#pragma unroll
      for (int j = 0; j < 8; ++j) {
        const float f = (float)v[j];
        const int lc = c8 * 8 + j;
#pragma unroll
        for (int m = 0; m < 8; ++m) s[m] = fmaf(f, ms[m * 128 + lc], s[m]);
      }
    }
#pragma unroll
    for (int m = 0; m < 8; ++m) s[m] += __shfl_xor(s[m], 1, 64);
    if (half == 0 && grow < N_NODES) {
      float* dst = simraw4 + (size_t)tn * SLICE + (size_t)grow * 8;
      f32x4 o0{s[0], s[1], s[2], s[3]};
      f32x4 o1{s[4], s[5], s[6], s[7]};
      *(f32x4*)dst = o0;
      *(f32x4*)(dst + 4) = o1;
    }
    return;
  }

  // epilogue: bias (+ relu) -> bf16 (and optionally fp8 via LDS repack)
  if (H8) __syncthreads();        // all waves done with ring LDS before overwrite
#pragma unroll
  for (int ni = 0; ni < 4; ++ni) {
    const int lcol = wn * 64 + ni * 16 + rl;
    const int col = tn * 128 + lcol;
    const float bv_ = bias[col];
#pragma unroll
    for (int mi = 0; mi < 4; ++mi) {
      const int lrowb = wm * 64 + mi * 16 + rg;
      const int rowb = tm * 128 + lrowb;
#pragma unroll
      for (int r = 0; r < 4; ++r) {
        float v = acc[mi][ni][r] + bv_;
        if (RELU) v = fmaxf(v, 0.f);
        const __bf16 bvv = (__bf16)v;
        C[(size_t)(rowb + r) * NH + col] = bvv;
        if (H8) rep[(lrowb + r) * 132 + lcol] = bvv;
      }
    }
  }
  if (H8) {
    __syncthreads();
    const int lrow = tid >> 1;
    const int row_g = tm * 128 + lrow;
    if (row_g < N_NODES) {
      const __bf16* srcp = rep + lrow * 132 + (tid & 1) * 64;
      unsigned dw[16];
#pragma unroll
      for (int q = 0; q < 16; ++q) {
        int w = 0;
        w = __builtin_amdgcn_cvt_pk_fp8_f32((float)srcp[q*4+0], (float)srcp[q*4+1], w, false);
        w = __builtin_amdgcn_cvt_pk_fp8_f32((float)srcp[q*4+2], (float)srcp[q*4+3], w, true);
        dw[q] = (unsigned)w;
      }
      unsigned* dstp = C8 + (size_t)row_g * 128 + (tn * 128 + (tid & 1) * 64) / 4;
#pragma unroll
      for (int q = 0; q < 4; ++q)
        *(uint4*)(dstp + q * 4) = uint4{dw[q*4], dw[q*4+1], dw[q*4+2], dw[q*4+3]};
    }
  }
}

// ---------------- smpool: softmax(sum of 4 simraw slices) -> (sim0?) + pooling -----------
template<bool WRITE_SIM>
__global__ __launch_bounds__(256) void smpool_kernel(const float* __restrict__ simraw4,
                                                     const float* __restrict__ mem,
                                                     const int* __restrict__ batch,
                                                     unsigned* __restrict__ gmax,
                                                     float* __restrict__ gsum,
                                                     int colofs,
                                                     float* __restrict__ simout) {
  __shared__ float sm[8 * 512];
  const int tid = threadIdx.x;
  for (int i = tid; i < 4096; i += 256) sm[i] = mem[i];
  __syncthreads();
  const int lane = tid & 63;
  const int n0 = blockIdx.x * 128 + (tid >> 6) * 32;
  const int nend = min(n0 + 32, N_NODES);

  float mx[8], sv[8];
#pragma unroll
  for (int j = 0; j < 8; ++j) { mx[j] = -3.0e38f; sv[j] = 0.f; }
  int cur = -1;

  for (int n = n0; n < nend; ++n) {
    const int g = batch[n];
    if (g != cur) {
      if (cur >= 0) {
#pragma unroll
        for (int j = 0; j < 8; ++j) {
          atomicMax(&gmax[(size_t)cur * 1024 + colofs + lane + j * 64], enc_f32(mx[j]));
          atomicAdd(&gsum[(size_t)cur * 1024 + colofs + lane + j * 64], sv[j]);
        }
      }
      cur = g;
#pragma unroll
      for (int j = 0; j < 8; ++j) { mx[j] = -3.0e38f; sv[j] = 0.f; }
    }
    f32x4 r0 = f32x4{0.f,0.f,0.f,0.f}, r1 = f32x4{0.f,0.f,0.f,0.f};
    const float* sp = simraw4 + (size_t)n * 8;
#pragma unroll
    for (int sl = 0; sl < 4; ++sl) {
      r0 += *(const f32x4*)(sp + (size_t)sl * SLICE);
      r1 += *(const f32x4*)(sp + (size_t)sl * SLICE + 4);
    }
    float w[8] = {r0[0],r0[1],r0[2],r0[3],r1[0],r1[1],r1[2],r1[3]};
    float smx = w[0];
#pragma unroll
    for (int m = 1; m < 8; ++m) smx = fmaxf(smx, w[m]);
    float ssum = 0.f;
#pragma unroll
    for (int m = 0; m < 8; ++m) { w[m] = __expf(w[m] - smx); ssum += w[m]; }
    const float inv = 1.f / ssum;
#pragma unroll
    for (int m = 0; m < 8; ++m) w[m] *= inv;
    if (WRITE_SIM && lane == 0) {
      f32x4 o0{w[0], w[1], w[2], w[3]};
      f32x4 o1{w[4], w[5], w[6], w[7]};
      *(f32x4*)(simout + (size_t)n * 8) = o0;
      *(f32x4*)(simout + (size_t)n * 8 + 4) = o1;
    }
    float outv[8] = {0.f,0.f,0.f,0.f,0.f,0.f,0.f,0.f};
#pragma unroll
    for (int m = 0; m < 8; ++m) {
      const float wm_ = w[m];
      const float* mr = sm + m * 512 + lane;
#pragma unroll
      for (int j = 0; j < 8; ++j) outv[j] += wm_ * mr[j * 64];
    }
#pragma unroll
    for (int j = 0; j < 8; ++j) {
      mx[j] = fmaxf(mx[j], outv[j]);
      sv[j] += outv[j];
    }
  }
  if (cur >= 0) {
#pragma unroll
    for (int j = 0; j < 8; ++j) {
      atomicMax(&gmax[(size_t)cur * 1024 + colofs + lane + j * 64], enc_f32(mx[j]));
      atomicAdd(&gsum[(size_t)cur * 1024 + colofs + lane + j * 64], sv[j]);
    }
  }
}

// ---------------- graph ranges (batch is sorted) ----------------
__global__ __launch_bounds__(256) void ranges_kernel(const int* __restrict__ batch,
                                                     int* __restrict__ gstart) {
  int g = blockIdx.x * 256 + threadIdx.x;
  if (g > N_GRAPH) return;
  if (g == N_GRAPH) { gstart[N_GRAPH] = N_NODES; return; }
  int lo = 0, hi = N_NODES;
  while (lo < hi) {
    int mid = (lo + hi) >> 1;
    if (batch[mid] < g) lo = mid + 1; else hi = mid;
  }
  gstart[g] = lo;
}

// ---------------- pooling decode: gf [G][2048] = [max | mean] ----------------
__global__ __launch_bounds__(256) void pool2_kernel(const unsigned* __restrict__ gmax,
                                                    const float* __restrict__ gsum,
                                                    const int* __restrict__ gstart,
                                                    float* __restrict__ g) {
  const int gr = blockIdx.x;
  const int t = threadIdx.x;
  const int cnt = gstart[gr + 1] - gstart[gr];
  const float inv = 1.f / fmaxf((float)cnt, 1.f);
#pragma unroll
  for (int j = 0; j < 4; ++j) {
    const int f = t * 4 + j;
    unsigned u = gmax[(size_t)gr * 1024 + f];
    g[(size_t)gr * 2048 + f] = (cnt > 0) ? dec_f32(u) : 0.f;
    g[(size_t)gr * 2048 + 1024 + f] = gsum[(size_t)gr * 1024 + f] * inv;
  }
}

// ---------------- classifier head: log_softmax(g @ lin_w + lin_b) ----------------
__global__ __launch_bounds__(64) void classify_kernel(const float* __restrict__ g,
                                                      const float* __restrict__ lw,
                                                      const float* __restrict__ lb,
                                                      float* __restrict__ out) {
  const int gr = blockIdx.x;
  const int lane = threadIdx.x;   // 64
  float acc[10];
  for (int c = 0; c < 10; ++c) acc[c] = 0.f;
  const float* grow = g + (size_t)gr * 2048;
  for (int k = lane; k < 2048; k += 64) {
    float gv = grow[k];
    const float* w = lw + (size_t)k * 10;
#pragma unroll
    for (int c = 0; c < 10; ++c) acc[c] += gv * w[c];
  }
  for (int c = 0; c < 10; ++c)
    for (int off = 32; off; off >>= 1) acc[c] += __shfl_xor(acc[c], off, 64);
  if (lane == 0) {
    float lg[10];
    float mx = -3.0e38f;
    for (int c = 0; c < 10; ++c) { lg[c] = acc[c] + lb[c]; mx = fmaxf(mx, lg[c]); }
    float s = 0.f;
    for (int c = 0; c < 10; ++c) s += expf(lg[c] - mx);
    float lse = logf(s);
    for (int c = 0; c < 10; ++c) out[(size_t)gr * 10 + c] = lg[c] - mx - lse;
  }
}

// =======================================================================================
extern "C" void kernel_launch(void* const* d_in, const int* in_sizes, int n_in,
                              void* d_out, int out_size, void* d_ws, size_t ws_size,
                              hipStream_t stream) {
  (void)in_sizes; (void)n_in; (void)out_size; (void)ws_size;
  const float* x      = (const float*)d_in[0];
  const int*   eidx   = (const int*)d_in[1];
  const int*   batch  = (const int*)d_in[2];
  const float* pre_w  = (const float*)d_in[4];
  const float* pre_b  = (const float*)d_in[5];
  const float* w1_0   = (const float*)d_in[6];
  const float* b1_0   = (const float*)d_in[7];
  const float* w2_0   = (const float*)d_in[8];
  const float* b2_0   = (const float*)d_in[9];
  const float* mem_0  = (const float*)d_in[10];
  const float* w1_1   = (const float*)d_in[11];
  const float* b1_1   = (const float*)d_in[12];
  const float* w2_1   = (const float*)d_in[13];
  const float* b2_1   = (const float*)d_in[14];
  const float* mem_1  = (const float*)d_in[15];
  const float* lin_w  = (const float*)d_in[16];
  const float* lin_b  = (const float*)d_in[17];
  float* out = (float*)d_out;

  const int* src = eidx;
  const int* dst = eidx + N_EDGES;

  // ---- workspace carve ----
  char* p = (char*)d_ws;
  auto alloc = [&](size_t bytes) -> char* {
    char* r = p;
    p += (bytes + 255) & ~(size_t)255;
    return r;
  };
  __bf16* xb    = (__bf16*)alloc((size_t)MP * 512 * 2);
  __bf16* hb    = (__bf16*)alloc((size_t)MP * 512 * 2);
  __bf16* aggb  = (__bf16*)alloc((size_t)MP * 512 * 2);
  __bf16* y1b   = (__bf16*)alloc((size_t)MP * 512 * 2);
  unsigned* h8  = (unsigned*)alloc((size_t)N_NODES * 512);
  __bf16* preT  = (__bf16*)alloc((size_t)512 * 512 * 2);
  __bf16* w1T0  = (__bf16*)alloc((size_t)512 * 1024 * 2);
  __bf16* w2T0  = (__bf16*)alloc((size_t)512 * 512 * 2);
  __bf16* w2T1  = (__bf16*)alloc((size_t)512 * 512 * 2);
  int* deg      = (int*)alloc((size_t)N_NODES * 4);
  int* rowstart = (int*)alloc((size_t)(N_NODES + 1) * 4);
  int* cursor   = (int*)alloc((size_t)N_NODES * 4);
  int* bsum     = (int*)alloc(128 * 4);
  int* csr      = (int*)alloc((size_t)N_EDGES * 4);
  int* gstart   = (int*)alloc((size_t)(N_GRAPH + 1) * 4);
  float* gf     = (float*)alloc((size_t)N_GRAPH * 2048 * 4);
  unsigned* gmax = (unsigned*)alloc((size_t)N_GRAPH * 1024 * 4);
  float* gsum    = (float*)alloc((size_t)N_GRAPH * 1024 * 4);
  float* sim0    = (float*)alloc((size_t)N_NODES * 8 * 4);
  float* simraw4 = (float*)alloc((size_t)4 * N_NODES * 8 * 4);
  float* aggS    = (float*)alloc((size_t)N_NODES * 8 * 4);
  float* UV      = (float*)alloc((size_t)16 * 512 * 4);

  // ---- dynamic LDS: 64KB ring (+4KB mem slice for SIM) ----
  const int GEMM_LDS = 69632;
  hipFuncSetAttribute(reinterpret_cast<const void*>(&gemm128_kernel<512,  false, false, true,  false>),
                      hipFuncAttributeMaxDynamicSharedMemorySize, GEMM_LDS);
  hipFuncSetAttribute(reinterpret_cast<const void*>(&gemm128_kernel<1024, true,  true,  false, false>),
                      hipFuncAttributeMaxDynamicSharedMemorySize, GEMM_LDS);
  hipFuncSetAttribute(reinterpret_cast<const void*>(&gemm128_kernel<512,  false, true,  false, true>),
                      hipFuncAttributeMaxDynamicSharedMemorySize, GEMM_LDS);

  // ---- weight prep ----
  transpose_kernel<<<dim3(16, 16), 256, 0, stream>>>(pre_w, preT, 512, 512);
  transpose_kernel<<<dim3(16, 32), 256, 0, stream>>>(w1_0, w1T0, 1024, 512);
  transpose_kernel<<<dim3(16, 16), 256, 0, stream>>>(w2_0, w2T0, 512, 512);
  transpose_kernel<<<dim3(16, 16), 256, 0, stream>>>(w2_1, w2T1, 512, 512);
  uv_kernel<<<16, 512, 0, stream>>>(mem_0, w1_1, UV);   // rank-8 tables for layer 1

  // ---- input cast ----
  castx_kernel<<<25024, 256, 0, stream>>>(x, xb);

  // ---- CSR build (per call; deterministic work) ----
  hipMemsetAsync(deg, 0, (size_t)N_NODES * 4, stream);
  degree_kernel<<<3125, 256, 0, stream>>>(dst, deg);
  scan1_kernel<<<98, 256, 0, stream>>>(deg, rowstart, bsum, N_NODES);
  scan2_kernel<<<1, 64, 0, stream>>>(bsum, 98);
  scan3_kernel<<<392, 256, 0, stream>>>(rowstart, bsum, cursor, N_NODES);
  scatter_kernel<<<3125, 256, 0, stream>>>(src, dst, cursor, csr);

  // pooling accumulators: gmax||gsum contiguous -> one memset
  hipMemsetAsync(gmax, 0, (size_t)N_GRAPH * 1024 * 4 * 2, stream);
  ranges_kernel<<<2, 256, 0, stream>>>(batch, gstart);

  const int GG = 1564;   // 391 M-tiles x 4 N-tiles

  // ---- pre conv: h = x @ pre_w + pre_b (emits bf16 + fp8 copies) ----
  gemm128_kernel<512, false, false, true, false><<<GG, 256, GEMM_LDS, stream>>>(
      xb, nullptr, preT, pre_b, hb, h8, nullptr, nullptr);

  // ---- layer 0 ----
  aggregate8_kernel<<<25000, 256, 0, stream>>>(h8, rowstart, csr, aggb);
  gemm128_kernel<1024, true, true, false, false><<<GG, 256, GEMM_LDS, stream>>>(
      hb, aggb, w1T0, b1_0, y1b, nullptr, nullptr, nullptr);
  gemm128_kernel<512, false, true, false, true><<<GG, 256, GEMM_LDS, stream>>>(
      y1b, nullptr, w2T0, b2_0, nullptr, nullptr, mem_0, simraw4);
  smpool_kernel<true><<<782, 256, 0, stream>>>(simraw4, mem_0, batch, gmax, gsum, 0, sim0);

  // ---- layer 1 (rank-8 collapsed front half) ----
  aggsim_kernel<<<391, 256, 0, stream>>>(sim0, rowstart, csr, aggS);
  z1y_kernel<<<25000, 256, 0, stream>>>(sim0, aggS, UV, b1_1, y1b);
  gemm128_kernel<512, false, true, false, true><<<GG, 256, GEMM_LDS, stream>>>(
      y1b, nullptr, w2T1, b2_1, nullptr, nullptr, mem_1, simraw4);
  smpool_kernel<false><<<782, 256, 0, stream>>>(simraw4, mem_1, batch, gmax, gsum, 512, nullptr);

  // ---- readout ----
  pool2_kernel<<<N_GRAPH, 256, 0, stream>>>(gmax, gsum, gstart, gf);
  classify_kernel<<<N_GRAPH, 64, 0, stream>>>(gf, lin_w, lin_b, out);
}

// Round 18
// 707.700 us; speedup vs baseline: 1.0802x; 1.0544x over previous
//
#include <hip/hip_runtime.h>

#define N_NODES 100000
#define N_EDGES 800000
#define N_GRAPH 256
#define MP      100096   // 391 * 256, padded M
#define NH      512

typedef __bf16 bf16x4v __attribute__((ext_vector_type(4)));
typedef __bf16 bf16x8v __attribute__((ext_vector_type(8)));
typedef float  f32x4   __attribute__((ext_vector_type(4)));
typedef float  f32x2   __attribute__((ext_vector_type(2)));

__device__ __forceinline__ void gload_lds16(const void* g, void* l) {
  __builtin_amdgcn_global_load_lds((const __attribute__((address_space(1))) void*)g,
                                   (__attribute__((address_space(3))) void*)l, 16, 0, 0);
}

// order-preserving fp32 <-> uint32 encoding for atomicMax
__device__ __forceinline__ unsigned enc_f32(float f) {
  unsigned u = __float_as_uint(f);
  return (u & 0x80000000u) ? ~u : (u | 0x80000000u);
}
__device__ __forceinline__ float dec_f32(unsigned u) {
  return (u & 0x80000000u) ? __uint_as_float(u & 0x7FFFFFFFu) : __uint_as_float(~u);
}

// ---------------- cast x (fp32) -> padded bf16 [MP][512] ----------------
__global__ __launch_bounds__(256) void castx_kernel(const float* __restrict__ x,
                                                    __bf16* __restrict__ xb) {
  const size_t i = (size_t)blockIdx.x * 256 + threadIdx.x;   // 8-elem chunk id
  const size_t row = i >> 6;
  const int c = (int)(i & 63) * 8;
  if (row >= MP) return;
  bf16x8v o;
  if (row < N_NODES) {
    const float* p = x + row * 512 + c;
    f32x4 a = *(const f32x4*)p;
    f32x4 b = *(const f32x4*)(p + 4);
    o[0]=(__bf16)a[0]; o[1]=(__bf16)a[1]; o[2]=(__bf16)a[2]; o[3]=(__bf16)a[3];
    o[4]=(__bf16)b[0]; o[5]=(__bf16)b[1]; o[6]=(__bf16)b[2]; o[7]=(__bf16)b[3];
  } else {
    for (int j = 0; j < 8; ++j) o[j] = (__bf16)0.0f;
  }
  *(bf16x8v*)(xb + row * 512 + c) = o;
}

// ---------------- cast mem (fp32 [8][512]) -> bf16 [16][512], rows 8..15 zero ------------
__global__ __launch_bounds__(256) void castmem_kernel(const float* __restrict__ mem,
                                                      __bf16* __restrict__ memT) {
  const int row = blockIdx.x;   // 0..15
  for (int c = threadIdx.x; c < 512; c += 256)
    memT[(size_t)row * 512 + c] = (row < 8) ? (__bf16)mem[(size_t)row * 512 + c] : (__bf16)0.0f;
}

// ---------------- weight transpose: W[K][N] fp32 -> BT[N][K] bf16 ----------------
__global__ __launch_bounds__(256) void transpose_kernel(const float* __restrict__ W,
                                                        __bf16* __restrict__ BT,
                                                        int K, int Nn) {
  __shared__ float tile[32][33];
  const int bx = blockIdx.x;   // n tile
  const int by = blockIdx.y;   // k tile
  const int tx = threadIdx.x & 31;
  const int ty = threadIdx.x >> 5;   // 0..7
  for (int j = 0; j < 4; ++j) {
    int k = by * 32 + ty + j * 8;
    int n = bx * 32 + tx;
    tile[ty + j * 8][tx] = W[(size_t)k * Nn + n];
  }
  __syncthreads();
  for (int j = 0; j < 4; ++j) {
    int n = bx * 32 + ty + j * 8;
    int k = by * 32 + tx;
    BT[(size_t)n * K + k] = (__bf16)tile[tx][ty + j * 8];
  }
}

// ---------------- CSR build ----------------
__global__ __launch_bounds__(256) void degree_kernel(const int* __restrict__ dst,
                                                     int* __restrict__ deg) {
  int e = blockIdx.x * 256 + threadIdx.x;
  if (e < N_EDGES) atomicAdd(&deg[dst[e]], 1);
}

__global__ __launch_bounds__(256) void scan1_kernel(const int* __restrict__ deg,
                                                    int* __restrict__ rs,
                                                    int* __restrict__ bsum, int n) {
  __shared__ int lds[256];
  const int b = blockIdx.x, t = threadIdx.x;
  const int base = b * 1024 + t * 4;
  int v[4];
  for (int j = 0; j < 4; ++j) v[j] = (base + j < n) ? deg[base + j] : 0;
  int tsum = v[0] + v[1] + v[2] + v[3];
  lds[t] = tsum;
  __syncthreads();
  for (int off = 1; off < 256; off <<= 1) {
    int x = 0;
    if (t >= off) x = lds[t - off];
    __syncthreads();
    lds[t] += x;
    __syncthreads();
  }
  int run = lds[t] - tsum;   // exclusive prefix of this thread
  for (int j = 0; j < 4; ++j) {
    if (base + j < n) rs[base + j] = run;
    run += v[j];
  }
  if (t == 255) bsum[b] = lds[255];
}

__global__ void scan2_kernel(int* bsum, int nb) {
  if (threadIdx.x == 0 && blockIdx.x == 0) {
    int run = 0;
    for (int i = 0; i < nb; ++i) { int v = bsum[i]; bsum[i] = run; run += v; }
  }
}

__global__ __launch_bounds__(256) void scan3_kernel(int* __restrict__ rs,
                                                    const int* __restrict__ bsum,
                                                    int* __restrict__ cursor, int n) {
  int i = blockIdx.x * 256 + threadIdx.x;
  if (i < n) {
    int v = rs[i] + bsum[i >> 10];
    rs[i] = v;
    cursor[i] = v;
  } else if (i == n) {
    rs[n] = N_EDGES;
  }
}

__global__ __launch_bounds__(256) void scatter_kernel(const int* __restrict__ src,
                                                      const int* __restrict__ dst,
                                                      int* __restrict__ cursor,
                                                      int* __restrict__ csr) {
  int e = blockIdx.x * 256 + threadIdx.x;
  if (e < N_EDGES) {
    int slot = atomicAdd(&cursor[dst[e]], 1);
    csr[slot] = src[e];
  }
}

// ---------------- aggregate (fp8 gather): agg[n] = sum_{e: dst==n} h8[src[e]] ------------
__global__ __launch_bounds__(256) void aggregate8_kernel(const unsigned* __restrict__ h8,
                                                         const int* __restrict__ rs,
                                                         const int* __restrict__ csr,
                                                         __bf16* __restrict__ agg) {
  const int node = blockIdx.x * 4 + (threadIdx.x >> 6);
  if (node >= N_NODES) return;
  const int lane = threadIdx.x & 63;
  const int s = rs[node], e = rs[node + 1];
  float acc[8] = {0.f,0.f,0.f,0.f,0.f,0.f,0.f,0.f};
  const size_t lofs = (size_t)lane * 2;     // 8 fp8 = 2 dwords per lane
  for (int i = s; i < e; i += 4) {
    const int i1 = (i + 1 < e) ? i + 1 : i;
    const int i2 = (i + 2 < e) ? i + 2 : i;
    const int i3 = (i + 3 < e) ? i + 3 : i;
    const float w1 = (i + 1 < e) ? 1.f : 0.f;
    const float w2 = (i + 2 < e) ? 1.f : 0.f;
    const float w3 = (i + 3 < e) ? 1.f : 0.f;
    const int n0 = csr[i], n1 = csr[i1], n2 = csr[i2], n3 = csr[i3];
    uint2 u0 = *(const uint2*)(h8 + (size_t)n0 * 128 + lofs);
    uint2 u1 = *(const uint2*)(h8 + (size_t)n1 * 128 + lofs);
    uint2 u2 = *(const uint2*)(h8 + (size_t)n2 * 128 + lofs);
    uint2 u3 = *(const uint2*)(h8 + (size_t)n3 * 128 + lofs);

    f32x2 a, b, c, d;
    a = __builtin_amdgcn_cvt_pk_f32_fp8((int)u0.x, false);
    b = __builtin_amdgcn_cvt_pk_f32_fp8((int)u0.x, true);
    c = __builtin_amdgcn_cvt_pk_f32_fp8((int)u0.y, false);
    d = __builtin_amdgcn_cvt_pk_f32_fp8((int)u0.y, true);
    acc[0]+=a[0]; acc[1]+=a[1]; acc[2]+=b[0]; acc[3]+=b[1];
    acc[4]+=c[0]; acc[5]+=c[1]; acc[6]+=d[0]; acc[7]+=d[1];

    a = __builtin_amdgcn_cvt_pk_f32_fp8((int)u1.x, false);
    b = __builtin_amdgcn_cvt_pk_f32_fp8((int)u1.x, true);
    c = __builtin_amdgcn_cvt_pk_f32_fp8((int)u1.y, false);
    d = __builtin_amdgcn_cvt_pk_f32_fp8((int)u1.y, true);
    acc[0]=fmaf(w1,a[0],acc[0]); acc[1]=fmaf(w1,a[1],acc[1]);
    acc[2]=fmaf(w1,b[0],acc[2]); acc[3]=fmaf(w1,b[1],acc[3]);
    acc[4]=fmaf(w1,c[0],acc[4]); acc[5]=fmaf(w1,c[1],acc[5]);
    acc[6]=fmaf(w1,d[0],acc[6]); acc[7]=fmaf(w1,d[1],acc[7]);

    a = __builtin_amdgcn_cvt_pk_f32_fp8((int)u2.x, false);
    b = __builtin_amdgcn_cvt_pk_f32_fp8((int)u2.x, true);
    c = __builtin_amdgcn_cvt_pk_f32_fp8((int)u2.y, false);
    d = __builtin_amdgcn_cvt_pk_f32_fp8((int)u2.y, true);
    acc[0]=fmaf(w2,a[0],acc[0]); acc[1]=fmaf(w2,a[1],acc[1]);
    acc[2]=fmaf(w2,b[0],acc[2]); acc[3]=fmaf(w2,b[1],acc[3]);
    acc[4]=fmaf(w2,c[0],acc[4]); acc[5]=fmaf(w2,c[1],acc[5]);
    acc[6]=fmaf(w2,d[0],acc[6]); acc[7]=fmaf(w2,d[1],acc[7]);

    a = __builtin_amdgcn_cvt_pk_f32_fp8((int)u3.x, false);
    b = __builtin_amdgcn_cvt_pk_f32_fp8((int)u3.x, true);
    c = __builtin_amdgcn_cvt_pk_f32_fp8((int)u3.y, false);
    d = __builtin_amdgcn_cvt_pk_f32_fp8((int)u3.y, true);
    acc[0]=fmaf(w3,a[0],acc[0]); acc[1]=fmaf(w3,a[1],acc[1]);
    acc[2]=fmaf(w3,b[0],acc[2]); acc[3]=fmaf(w3,b[1],acc[3]);
    acc[4]=fmaf(w3,c[0],acc[4]); acc[5]=fmaf(w3,c[1],acc[5]);
    acc[6]=fmaf(w3,d[0],acc[6]); acc[7]=fmaf(w3,d[1],acc[7]);
  }
  bf16x8v o;
#pragma unroll
  for (int j = 0; j < 8; ++j) o[j] = (__bf16)acc[j];
  *(bf16x8v*)(agg + (size_t)node * 512 + (size_t)lane * 8) = o;
}

// ---------------- aggregate (layer 1, rank-8): aggS[n] = sum sim0[src] ----------------
__global__ __launch_bounds__(256) void aggsim_kernel(const float* __restrict__ sim,
                                                     const int* __restrict__ rs,
                                                     const int* __restrict__ csr,
                                                     float* __restrict__ aggS) {
  const int node = blockIdx.x * 256 + threadIdx.x;
  if (node >= N_NODES) return;
  f32x4 a0 = f32x4{0.f,0.f,0.f,0.f}, a1 = f32x4{0.f,0.f,0.f,0.f};
  const int s = rs[node], e = rs[node + 1];
  for (int i = s; i < e; ++i) {
    const int sn = csr[i];
    a0 += *(const f32x4*)(sim + (size_t)sn * 8);
    a1 += *(const f32x4*)(sim + (size_t)sn * 8 + 4);
  }
  *(f32x4*)(aggS + (size_t)node * 8) = a0;
  *(f32x4*)(aggS + (size_t)node * 8 + 4) = a1;
}

// ---------------- UV: U[m] = mem0[m] @ W1_1[0:512], V[m] = mem0[m] @ W1_1[512:1024] -----
__global__ __launch_bounds__(512) void uv_kernel(const float* __restrict__ mem,
                                                 const float* __restrict__ w1,
                                                 float* __restrict__ UV) {
  const int mu = blockIdx.x;        // 0..15
  const int c  = threadIdx.x;       // 0..511
  const int m = mu & 7, half = mu >> 3;
  const float* wbase = w1 + (size_t)(half * 512) * 512;
  const float* mrow  = mem + (size_t)m * 512;
  float acc = 0.f;
  for (int k = 0; k < 512; ++k) acc += mrow[k] * wbase[(size_t)k * 512 + c];
  UV[(size_t)mu * 512 + c] = acc;
}

// ---------------- z1y: y1 = relu(sim0 @ U + aggS @ V + b1), [N,512] bf16 ----------------
__global__ __launch_bounds__(256) void z1y_kernel(const float* __restrict__ sim,
                                                  const float* __restrict__ aggS,
                                                  const float* __restrict__ UV,
                                                  const float* __restrict__ b1,
                                                  __bf16* __restrict__ y) {
  __shared__ float suv[16 * 512];   // 32KB
  __shared__ float sb[512];
  const int tid = threadIdx.x;
  for (int i = tid; i < 8192; i += 256) suv[i] = UV[i];
  for (int i = tid; i < 512; i += 256) sb[i] = b1[i];
  __syncthreads();
  const int node = blockIdx.x * 4 + (tid >> 6);
  if (node >= N_NODES) return;
  const int lane = tid & 63;
  f32x4 s0 = *(const f32x4*)(sim + (size_t)node * 8);
  f32x4 s1 = *(const f32x4*)(sim + (size_t)node * 8 + 4);
  f32x4 a0 = *(const f32x4*)(aggS + (size_t)node * 8);
  f32x4 a1 = *(const f32x4*)(aggS + (size_t)node * 8 + 4);
  float sv[8] = {s0[0],s0[1],s0[2],s0[3],s1[0],s1[1],s1[2],s1[3]};
  float av[8] = {a0[0],a0[1],a0[2],a0[3],a1[0],a1[1],a1[2],a1[3]};
  __bf16* yrow = y + (size_t)node * 512;
#pragma unroll
  for (int j = 0; j < 8; ++j) {
    const int c = lane + j * 64;
    float acc = sb[c];
#pragma unroll
    for (int m = 0; m < 8; ++m) {
      acc += sv[m] * suv[m * 512 + c];
      acc += av[m] * suv[(8 + m) * 512 + c];
    }
    yrow[c] = (__bf16)fmaxf(acc, 0.f);
  }
}

// ---------------- GEMM 128x128, BK=32, ring-4 depth-3, 64KB LDS -> 2 blocks/CU ----------
// C[M][512] = relu?( A @ BT^T + bias ), bf16 in/out, fp32 acc.
// H8: epilogue additionally emits fp8-e4m3 copy of C (via LDS repack; ring is dead
// post-loop, guarded by __syncthreads).
template<int KTOT, bool SPLIT, bool RELU, bool H8>
__global__ __launch_bounds__(256, 2) void gemm128_kernel(const __bf16* __restrict__ A1,
                                                         const __bf16* __restrict__ A2,
                                                         const __bf16* __restrict__ BT,
                                                         const float* __restrict__ bias,
                                                         __bf16* __restrict__ C,
                                                         unsigned* __restrict__ C8) {
  extern __shared__ char smem[];
  __bf16* As = (__bf16*)smem;              // 4 slots * 8KB = 32KB
  __bf16* Bs = (__bf16*)(smem + 32768);    // 32KB
  const int tid  = threadIdx.x;
  const int wid  = tid >> 6;     // 0..3
  const int lane = tid & 63;
  const int wm = wid >> 1;       // 0..1
  const int wn = wid & 1;        // 0..1
  const int srow = tid >> 2;     // 0..63 (row within 64-row half)
  const int scol = ((tid & 3) ^ ((tid >> 3) & 3)) * 8;   // inverse-swizzled source chunk
  const int rl  = lane & 15;
  const int rdk = (((lane >> 4) ^ ((lane >> 1) & 3)) * 8);  // swizzled read chunk

  // XCD-aware bijective remap (1564 = 4*196 + 4*195); the 4 N-tiles of a tm share an XCD
  const int bid = blockIdx.x;
  const int xcd = bid & 7, pos = bid >> 3;
  const int idx = (xcd < 4) ? (xcd * 196 + pos) : (784 + (xcd - 4) * 195 + pos);
  const int tm = idx >> 2, tn = idx & 3;

  constexpr int NT = KTOT / 32;

  f32x4 acc[4][4];
#pragma unroll
  for (int mi = 0; mi < 4; ++mi)
#pragma unroll
    for (int ni = 0; ni < 4; ++ni)
      acc[mi][ni] = f32x4{0.f, 0.f, 0.f, 0.f};

  auto stage = [&](int tk) {
    const int slot = tk & 3;
    const __bf16* Ap = A1;
    int kc = tk * 32;
    if (SPLIT && tk >= NT / 2) { Ap = A2; kc -= 512; }
#pragma unroll
    for (int j = 0; j < 2; ++j) {
      const __bf16* g = Ap + (size_t)(tm * 128 + j * 64 + srow) * NH + (kc + scol);
      gload_lds16(g, (char*)As + slot * 8192 + j * 4096 + wid * 1024);
    }
#pragma unroll
    for (int j = 0; j < 2; ++j) {
      const __bf16* g = BT + (size_t)(tn * 128 + j * 64 + srow) * KTOT + (tk * 32 + scol);
      gload_lds16(g, (char*)Bs + slot * 8192 + j * 4096 + wid * 1024);
    }
  };

  // prologue: fill 3 slots (12 loads in flight)
  stage(0); stage(1); stage(2);

  for (int tk = 0; tk < NT; ++tk) {
    if (tk < NT - 2)       asm volatile("s_waitcnt vmcnt(8)" ::: "memory");
    else if (tk == NT - 2) asm volatile("s_waitcnt vmcnt(4)" ::: "memory");
    else                   asm volatile("s_waitcnt vmcnt(0)" ::: "memory");
    __builtin_amdgcn_s_barrier();            // tile tk landed, tile tk-1 consumed
    asm volatile("" ::: "memory");           // pin LDS ops after the barrier

    if (tk + 3 < NT) stage(tk + 3);          // overwrites slot (tk-1)&3 -- safe post-barrier

    const int slot = tk & 3;
    const __bf16* a0 = As + slot * 4096 + (wm * 64 + rl) * 32 + rdk;
    const __bf16* b0 = Bs + slot * 4096 + (wn * 64 + rl) * 32 + rdk;
    bf16x8v av[4], bv[4];
#pragma unroll
    for (int mi = 0; mi < 4; ++mi) av[mi] = *(const bf16x8v*)(a0 + mi * 16 * 32);
#pragma unroll
    for (int ni = 0; ni < 4; ++ni) bv[ni] = *(const bf16x8v*)(b0 + ni * 16 * 32);

    __builtin_amdgcn_s_setprio(1);
#pragma unroll
    for (int mi = 0; mi < 4; ++mi)
#pragma unroll
      for (int ni = 0; ni < 4; ++ni)
        acc[mi][ni] = __builtin_amdgcn_mfma_f32_16x16x32_bf16(av[mi], bv[ni], acc[mi][ni], 0, 0, 0);
    __builtin_amdgcn_s_setprio(0);
  }

  // epilogue: bias (+ relu) -> bf16 (and optionally fp8 via LDS repack)
  __bf16* rep = (__bf16*)smem;    // [128][132] bf16 = 33792B; ring dead after loop
  if (H8) __syncthreads();        // all waves done with ring LDS before overwrite
  const int rg = (lane >> 4) * 4;
#pragma unroll
  for (int ni = 0; ni < 4; ++ni) {
    const int lcol = wn * 64 + ni * 16 + rl;
    const int col = tn * 128 + lcol;
    const float bv_ = bias[col];
#pragma unroll
    for (int mi = 0; mi < 4; ++mi) {
      const int lrowb = wm * 64 + mi * 16 + rg;
      const int rowb = tm * 128 + lrowb;
#pragma unroll
      for (int r = 0; r < 4; ++r) {
        float v = acc[mi][ni][r] + bv_;
        if (RELU) v = fmaxf(v, 0.f);
        const __bf16 bvv = (__bf16)v;
        C[(size_t)(rowb + r) * NH + col] = bvv;
        if (H8) rep[(lrowb + r) * 132 + lcol] = bvv;
      }
    }
  }
  if (H8) {
    __syncthreads();
    const int lrow = tid >> 1;
    const int row_g = tm * 128 + lrow;
    if (row_g < N_NODES) {
      const __bf16* srcp = rep + lrow * 132 + (tid & 1) * 64;
      unsigned dw[16];
#pragma unroll
      for (int q = 0; q < 16; ++q) {
        int w = 0;
        w = __builtin_amdgcn_cvt_pk_fp8_f32((float)srcp[q*4+0], (float)srcp[q*4+1], w, false);
        w = __builtin_amdgcn_cvt_pk_fp8_f32((float)srcp[q*4+2], (float)srcp[q*4+3], w, true);
        dw[q] = (unsigned)w;
      }
      unsigned* dstp = C8 + (size_t)row_g * 128 + (tn * 128 + (tid & 1) * 64) / 4;
#pragma unroll
      for (int q = 0; q < 4; ++q)
        *(uint4*)(dstp + q * 4) = uint4{dw[q*4], dw[q*4+1], dw[q*4+2], dw[q*4+3]};
    }
  }
}

// ---------------- simgemm: simraw[N][8] = h @ mem^T (MFMA, N-dim=16 padded) -------------
__global__ __launch_bounds__(256, 3) void simgemm_kernel(const __bf16* __restrict__ A,
                                                         const __bf16* __restrict__ memT16,
                                                         float* __restrict__ simraw) {
  __shared__ __bf16 As[3 * 128 * 32];    // 24KB ring
  __shared__ __bf16 Bs[16 * 520];        // 16.25KB, padded rows
  const int tid  = threadIdx.x;
  const int wid  = tid >> 6;     // 0..3 (32 rows each)
  const int lane = tid & 63;
  const int srow = tid >> 2;     // 0..63
  const int scol = ((tid & 3) ^ ((tid >> 3) & 3)) * 8;      // inverse-swizzled source chunk
  const int rl  = lane & 15;
  const int rdk = (((lane >> 4) ^ ((lane >> 1) & 3)) * 8);  // swizzled read chunk (A)
  const int k8  = (lane >> 4) * 8;                           // plain chunk (B, padded rows)
  const int tm = blockIdx.x;
  constexpr int NT = 16;         // 512 / 32

  for (int i = tid; i < 16 * 512; i += 256) {
    const int r = i >> 9, c = i & 511;
    Bs[r * 520 + c] = memT16[i];
  }

  f32x4 acc[2];
  acc[0] = f32x4{0.f,0.f,0.f,0.f};
  acc[1] = f32x4{0.f,0.f,0.f,0.f};

  auto stage = [&](int tk) {
    const int slot = tk % 3;
#pragma unroll
    for (int j = 0; j < 2; ++j) {
      const __bf16* g = A + (size_t)(tm * 128 + j * 64 + srow) * NH + (tk * 32 + scol);
      gload_lds16(g, (char*)As + slot * 8192 + j * 4096 + wid * 1024);
    }
  };

  stage(0); stage(1);
  __syncthreads();               // drains Bs ds_writes AND syncs before ring use

  for (int tk = 0; tk < NT; ++tk) {
    if (tk < NT - 1) asm volatile("s_waitcnt vmcnt(2)" ::: "memory");
    else             asm volatile("s_waitcnt vmcnt(0)" ::: "memory");
    __builtin_amdgcn_s_barrier();
    asm volatile("" ::: "memory");

    if (tk + 2 < NT) stage(tk + 2);

    const int slot = tk % 3;
    const __bf16* a0 = As + slot * 4096 + (wid * 32 + rl) * 32 + rdk;
    bf16x8v av0 = *(const bf16x8v*)(a0);
    bf16x8v av1 = *(const bf16x8v*)(a0 + 16 * 32);
    bf16x8v bv  = *(const bf16x8v*)(Bs + rl * 520 + tk * 32 + k8);
    acc[0] = __builtin_amdgcn_mfma_f32_16x16x32_bf16(av0, bv, acc[0], 0, 0, 0);
    acc[1] = __builtin_amdgcn_mfma_f32_16x16x32_bf16(av1, bv, acc[1], 0, 0, 0);
  }

  const int rg = (lane >> 4) * 4;
  if (rl < 8) {
#pragma unroll
    for (int mi = 0; mi < 2; ++mi) {
      const int rowb = tm * 128 + wid * 32 + mi * 16 + rg;
#pragma unroll
      for (int r = 0; r < 4; ++r) {
        const int row = rowb + r;
        if (row < N_NODES) simraw[(size_t)row * 8 + rl] = acc[mi][r];
      }
    }
  }
}

// ---------------- smpool: softmax(simraw) -> (sim0?) + pooling of sim@mem ----------------
template<bool WRITE_SIM>
__global__ __launch_bounds__(256) void smpool_kernel(const float* __restrict__ simraw,
                                                     const float* __restrict__ mem,
                                                     const int* __restrict__ batch,
                                                     unsigned* __restrict__ gmax,
                                                     float* __restrict__ gsum,
                                                     int colofs,
                                                     float* __restrict__ simout) {
  __shared__ float sm[8 * 512];
  const int tid = threadIdx.x;
  for (int i = tid; i < 4096; i += 256) sm[i] = mem[i];
  __syncthreads();
  const int lane = tid & 63;
  const int n0 = blockIdx.x * 128 + (tid >> 6) * 32;
  const int nend = min(n0 + 32, N_NODES);

  float mx[8], sv[8];
#pragma unroll
  for (int j = 0; j < 8; ++j) { mx[j] = -3.0e38f; sv[j] = 0.f; }
  int cur = -1;

  for (int n = n0; n < nend; ++n) {
    const int g = batch[n];
    if (g != cur) {
      if (cur >= 0) {
#pragma unroll
        for (int j = 0; j < 8; ++j) {
          atomicMax(&gmax[(size_t)cur * 1024 + colofs + lane + j * 64], enc_f32(mx[j]));
          atomicAdd(&gsum[(size_t)cur * 1024 + colofs + lane + j * 64], sv[j]);
        }
      }
      cur = g;
#pragma unroll
      for (int j = 0; j < 8; ++j) { mx[j] = -3.0e38f; sv[j] = 0.f; }
    }
    f32x4 r0 = *(const f32x4*)(simraw + (size_t)n * 8);
    f32x4 r1 = *(const f32x4*)(simraw + (size_t)n * 8 + 4);
    float w[8] = {r0[0],r0[1],r0[2],r0[3],r1[0],r1[1],r1[2],r1[3]};
    float smx = w[0];
#pragma unroll
    for (int m = 1; m < 8; ++m) smx = fmaxf(smx, w[m]);
    float ssum = 0.f;
#pragma unroll
    for (int m = 0; m < 8; ++m) { w[m] = __expf(w[m] - smx); ssum += w[m]; }
    const float inv = 1.f / ssum;
#pragma unroll
    for (int m = 0; m < 8; ++m) w[m] *= inv;
    if (WRITE_SIM && lane == 0) {
      f32x4 o0{w[0], w[1], w[2], w[3]};
      f32x4 o1{w[4], w[5], w[6], w[7]};
      *(f32x4*)(simout + (size_t)n * 8) = o0;
      *(f32x4*)(simout + (size_t)n * 8 + 4) = o1;
    }
    float outv[8] = {0.f,0.f,0.f,0.f,0.f,0.f,0.f,0.f};
#pragma unroll
    for (int m = 0; m < 8; ++m) {
      const float wm_ = w[m];
      const float* mr = sm + m * 512 + lane;
#pragma unroll
      for (int j = 0; j < 8; ++j) outv[j] += wm_ * mr[j * 64];
    }
#pragma unroll
    for (int j = 0; j < 8; ++j) {
      mx[j] = fmaxf(mx[j], outv[j]);
      sv[j] += outv[j];
    }
  }
  if (cur >= 0) {
#pragma unroll
    for (int j = 0; j < 8; ++j) {
      atomicMax(&gmax[(size_t)cur * 1024 + colofs + lane + j * 64], enc_f32(mx[j]));
      atomicAdd(&gsum[(size_t)cur * 1024 + colofs + lane + j * 64], sv[j]);
    }
  }
}

// ---------------- graph ranges (batch is sorted) ----------------
__global__ __launch_bounds__(256) void ranges_kernel(const int* __restrict__ batch,
                                                     int* __restrict__ gstart) {
  int g = blockIdx.x * 256 + threadIdx.x;
  if (g > N_GRAPH) return;
  if (g == N_GRAPH) { gstart[N_GRAPH] = N_NODES; return; }
  int lo = 0, hi = N_NODES;
  while (lo < hi) {
    int mid = (lo + hi) >> 1;
    if (batch[mid] < g) lo = mid + 1; else hi = mid;
  }
  gstart[g] = lo;
}

// ---------------- pooling decode: gf [G][2048] = [max | mean] ----------------
__global__ __launch_bounds__(256) void pool2_kernel(const unsigned* __restrict__ gmax,
                                                    const float* __restrict__ gsum,
                                                    const int* __restrict__ gstart,
                                                    float* __restrict__ g) {
  const int gr = blockIdx.x;
  const int t = threadIdx.x;
  const int cnt = gstart[gr + 1] - gstart[gr];
  const float inv = 1.f / fmaxf((float)cnt, 1.f);
#pragma unroll
  for (int j = 0; j < 4; ++j) {
    const int f = t * 4 + j;
    unsigned u = gmax[(size_t)gr * 1024 + f];
    g[(size_t)gr * 2048 + f] = (cnt > 0) ? dec_f32(u) : 0.f;
    g[(size_t)gr * 2048 + 1024 + f] = gsum[(size_t)gr * 1024 + f] * inv;
  }
}

// ---------------- classifier head: log_softmax(g @ lin_w + lin_b) ----------------
__global__ __launch_bounds__(64) void classify_kernel(const float* __restrict__ g,
                                                      const float* __restrict__ lw,
                                                      const float* __restrict__ lb,
                                                      float* __restrict__ out) {
  const int gr = blockIdx.x;
  const int lane = threadIdx.x;   // 64
  float acc[10];
  for (int c = 0; c < 10; ++c) acc[c] = 0.f;
  const float* grow = g + (size_t)gr * 2048;
  for (int k = lane; k < 2048; k += 64) {
    float gv = grow[k];
    const float* w = lw + (size_t)k * 10;
#pragma unroll
    for (int c = 0; c < 10; ++c) acc[c] += gv * w[c];
  }
  for (int c = 0; c < 10; ++c)
    for (int off = 32; off; off >>= 1) acc[c] += __shfl_xor(acc[c], off, 64);
  if (lane == 0) {
    float lg[10];
    float mx = -3.0e38f;
    for (int c = 0; c < 10; ++c) { lg[c] = acc[c] + lb[c]; mx = fmaxf(mx, lg[c]); }
    float s = 0.f;
    for (int c = 0; c < 10; ++c) s += expf(lg[c] - mx);
    float lse = logf(s);
    for (int c = 0; c < 10; ++c) out[(size_t)gr * 10 + c] = lg[c] - mx - lse;
  }
}

// =======================================================================================
extern "C" void kernel_launch(void* const* d_in, const int* in_sizes, int n_in,
                              void* d_out, int out_size, void* d_ws, size_t ws_size,
                              hipStream_t stream) {
  (void)in_sizes; (void)n_in; (void)out_size; (void)ws_size;
  const float* x      = (const float*)d_in[0];
  const int*   eidx   = (const int*)d_in[1];
  const int*   batch  = (const int*)d_in[2];
  const float* pre_w  = (const float*)d_in[4];
  const float* pre_b  = (const float*)d_in[5];
  const float* w1_0   = (const float*)d_in[6];
  const float* b1_0   = (const float*)d_in[7];
  const float* w2_0   = (const float*)d_in[8];
  const float* b2_0   = (const float*)d_in[9];
  const float* mem_0  = (const float*)d_in[10];
  const float* w1_1   = (const float*)d_in[11];
  const float* b1_1   = (const float*)d_in[12];
  const float* w2_1   = (const float*)d_in[13];
  const float* b2_1   = (const float*)d_in[14];
  const float* mem_1  = (const float*)d_in[15];
  const float* lin_w  = (const float*)d_in[16];
  const float* lin_b  = (const float*)d_in[17];
  float* out = (float*)d_out;

  const int* src = eidx;
  const int* dst = eidx + N_EDGES;

  // ---- workspace carve ----
  char* p = (char*)d_ws;
  auto alloc = [&](size_t bytes) -> char* {
    char* r = p;
    p += (bytes + 255) & ~(size_t)255;
    return r;
  };
  __bf16* xb    = (__bf16*)alloc((size_t)MP * 512 * 2);
  __bf16* hb    = (__bf16*)alloc((size_t)MP * 512 * 2);
  __bf16* aggb  = (__bf16*)alloc((size_t)MP * 512 * 2);
  __bf16* y1b   = (__bf16*)alloc((size_t)MP * 512 * 2);
  unsigned* h8  = (unsigned*)alloc((size_t)N_NODES * 512);
  __bf16* preT  = (__bf16*)alloc((size_t)512 * 512 * 2);
  __bf16* w1T0  = (__bf16*)alloc((size_t)512 * 1024 * 2);
  __bf16* w2T0  = (__bf16*)alloc((size_t)512 * 512 * 2);
  __bf16* w2T1  = (__bf16*)alloc((size_t)512 * 512 * 2);
  __bf16* memT0 = (__bf16*)alloc((size_t)16 * 512 * 2);
  __bf16* memT1 = (__bf16*)alloc((size_t)16 * 512 * 2);
  int* deg      = (int*)alloc((size_t)N_NODES * 4);
  int* rowstart = (int*)alloc((size_t)(N_NODES + 1) * 4);
  int* cursor   = (int*)alloc((size_t)N_NODES * 4);
  int* bsum     = (int*)alloc(128 * 4);
  int* csr      = (int*)alloc((size_t)N_EDGES * 4);
  int* gstart   = (int*)alloc((size_t)(N_GRAPH + 1) * 4);
  float* gf     = (float*)alloc((size_t)N_GRAPH * 2048 * 4);
  unsigned* gmax = (unsigned*)alloc((size_t)N_GRAPH * 1024 * 4);
  float* gsum    = (float*)alloc((size_t)N_GRAPH * 1024 * 4);
  float* sim0    = (float*)alloc((size_t)N_NODES * 8 * 4);
  float* simraw  = (float*)alloc((size_t)N_NODES * 8 * 4);
  float* aggS    = (float*)alloc((size_t)N_NODES * 8 * 4);
  float* UV      = (float*)alloc((size_t)16 * 512 * 4);

  // ---- dynamic LDS (64KB, ring-4) for the GEMM instantiations ----
  const int GEMM_LDS = 65536;
  hipFuncSetAttribute(reinterpret_cast<const void*>(&gemm128_kernel<512,  false, false, true>),
                      hipFuncAttributeMaxDynamicSharedMemorySize, GEMM_LDS);
  hipFuncSetAttribute(reinterpret_cast<const void*>(&gemm128_kernel<1024, true,  true,  false>),
                      hipFuncAttributeMaxDynamicSharedMemorySize, GEMM_LDS);
  hipFuncSetAttribute(reinterpret_cast<const void*>(&gemm128_kernel<512,  false, true,  false>),
                      hipFuncAttributeMaxDynamicSharedMemorySize, GEMM_LDS);

  // ---- weight prep ----
  transpose_kernel<<<dim3(16, 16), 256, 0, stream>>>(pre_w, preT, 512, 512);
  transpose_kernel<<<dim3(16, 32), 256, 0, stream>>>(w1_0, w1T0, 1024, 512);
  transpose_kernel<<<dim3(16, 16), 256, 0, stream>>>(w2_0, w2T0, 512, 512);
  transpose_kernel<<<dim3(16, 16), 256, 0, stream>>>(w2_1, w2T1, 512, 512);
  castmem_kernel<<<16, 256, 0, stream>>>(mem_0, memT0);
  castmem_kernel<<<16, 256, 0, stream>>>(mem_1, memT1);
  uv_kernel<<<16, 512, 0, stream>>>(mem_0, w1_1, UV);   // rank-8 tables for layer 1

  // ---- input cast ----
  castx_kernel<<<25024, 256, 0, stream>>>(x, xb);

  // ---- CSR build (per call; deterministic work) ----
  hipMemsetAsync(deg, 0, (size_t)N_NODES * 4, stream);
  degree_kernel<<<3125, 256, 0, stream>>>(dst, deg);
  scan1_kernel<<<98, 256, 0, stream>>>(deg, rowstart, bsum, N_NODES);
  scan2_kernel<<<1, 64, 0, stream>>>(bsum, 98);
  scan3_kernel<<<392, 256, 0, stream>>>(rowstart, bsum, cursor, N_NODES);
  scatter_kernel<<<3125, 256, 0, stream>>>(src, dst, cursor, csr);

  // pooling accumulators: gmax||gsum are contiguous -> one memset
  hipMemsetAsync(gmax, 0, (size_t)N_GRAPH * 1024 * 4 * 2, stream);
  ranges_kernel<<<2, 256, 0, stream>>>(batch, gstart);

  const int GG = 1564;   // 391 M-tiles x 4 N-tiles

  // ---- pre conv: h = x @ pre_w + pre_b (also emits fp8 copy for the gather) ----
  gemm128_kernel<512, false, false, true><<<GG, 256, GEMM_LDS, stream>>>(
      xb, nullptr, preT, pre_b, hb, h8);

  // ---- layer 0 ----
  aggregate8_kernel<<<25000, 256, 0, stream>>>(h8, rowstart, csr, aggb);
  gemm128_kernel<1024, true, true, false><<<GG, 256, GEMM_LDS, stream>>>(
      hb, aggb, w1T0, b1_0, y1b, nullptr);
  gemm128_kernel<512, false, true, false><<<GG, 256, GEMM_LDS, stream>>>(
      y1b, nullptr, w2T0, b2_0, hb, nullptr);
  simgemm_kernel<<<391, 256, 0, stream>>>(hb, memT0, simraw);
  smpool_kernel<true><<<782, 256, 0, stream>>>(simraw, mem_0, batch, gmax, gsum, 0, sim0);

  // ---- layer 1 (rank-8 collapsed front half) ----
  aggsim_kernel<<<391, 256, 0, stream>>>(sim0, rowstart, csr, aggS);
  z1y_kernel<<<25000, 256, 0, stream>>>(sim0, aggS, UV, b1_1, y1b);
  gemm128_kernel<512, false, true, false><<<GG, 256, GEMM_LDS, stream>>>(
      y1b, nullptr, w2T1, b2_1, hb, nullptr);
  simgemm_kernel<<<391, 256, 0, stream>>>(hb, memT1, simraw);
  smpool_kernel<false><<<782, 256, 0, stream>>>(simraw, mem_1, batch, gmax, gsum, 512, nullptr);

  // ---- readout ----
  pool2_kernel<<<N_GRAPH, 256, 0, stream>>>(gmax, gsum, gstart, gf);
  classify_kernel<<<N_GRAPH, 64, 0, stream>>>(gf, lin_w, lin_b, out);
}

// Round 19
// 676.499 us; speedup vs baseline: 1.1301x; 1.0461x over previous
//
#include <hip/hip_runtime.h>

#define N_NODES 100000
#define N_EDGES 800000
#define N_GRAPH 256
#define MP      100096   // 391 * 256, padded M
#define NH      512

typedef __bf16 bf16x4v __attribute__((ext_vector_type(4)));
typedef __bf16 bf16x8v __attribute__((ext_vector_type(8)));
typedef float  f32x4   __attribute__((ext_vector_type(4)));
typedef float  f32x2   __attribute__((ext_vector_type(2)));

__device__ __forceinline__ void gload_lds16(const void* g, void* l) {
  __builtin_amdgcn_global_load_lds((const __attribute__((address_space(1))) void*)g,
                                   (__attribute__((address_space(3))) void*)l, 16, 0, 0);
}

// order-preserving fp32 <-> uint32 encoding for atomicMax
__device__ __forceinline__ unsigned enc_f32(float f) {
  unsigned u = __float_as_uint(f);
  return (u & 0x80000000u) ? ~u : (u | 0x80000000u);
}
__device__ __forceinline__ float dec_f32(unsigned u) {
  return (u & 0x80000000u) ? __uint_as_float(u & 0x7FFFFFFFu) : __uint_as_float(~u);
}

// ---------------- cast mem (fp32 [8][512]) -> bf16 [16][512], rows 8..15 zero ------------
__global__ __launch_bounds__(256) void castmem_kernel(const float* __restrict__ mem,
                                                      __bf16* __restrict__ memT) {
  const int row = blockIdx.x;   // 0..15
  for (int c = threadIdx.x; c < 512; c += 256)
    memT[(size_t)row * 512 + c] = (row < 8) ? (__bf16)mem[(size_t)row * 512 + c] : (__bf16)0.0f;
}

// ---------------- weight transpose: W[K][N] fp32 -> BT[N][K] bf16 ----------------
__global__ __launch_bounds__(256) void transpose_kernel(const float* __restrict__ W,
                                                        __bf16* __restrict__ BT,
                                                        int K, int Nn) {
  __shared__ float tile[32][33];
  const int bx = blockIdx.x;   // n tile
  const int by = blockIdx.y;   // k tile
  const int tx = threadIdx.x & 31;
  const int ty = threadIdx.x >> 5;   // 0..7
  for (int j = 0; j < 4; ++j) {
    int k = by * 32 + ty + j * 8;
    int n = bx * 32 + tx;
    tile[ty + j * 8][tx] = W[(size_t)k * Nn + n];
  }
  __syncthreads();
  for (int j = 0; j < 4; ++j) {
    int n = bx * 32 + ty + j * 8;
    int k = by * 32 + tx;
    BT[(size_t)n * K + k] = (__bf16)tile[tx][ty + j * 8];
  }
}

// ---------------- CSR build ----------------
__global__ __launch_bounds__(256) void degree_kernel(const int* __restrict__ dst,
                                                     int* __restrict__ deg) {
  int e = blockIdx.x * 256 + threadIdx.x;
  if (e < N_EDGES) atomicAdd(&deg[dst[e]], 1);
}

__global__ __launch_bounds__(256) void scan1_kernel(const int* __restrict__ deg,
                                                    int* __restrict__ rs,
                                                    int* __restrict__ bsum, int n) {
  __shared__ int lds[256];
  const int b = blockIdx.x, t = threadIdx.x;
  const int base = b * 1024 + t * 4;
  int v[4];
  for (int j = 0; j < 4; ++j) v[j] = (base + j < n) ? deg[base + j] : 0;
  int tsum = v[0] + v[1] + v[2] + v[3];
  lds[t] = tsum;
  __syncthreads();
  for (int off = 1; off < 256; off <<= 1) {
    int x = 0;
    if (t >= off) x = lds[t - off];
    __syncthreads();
    lds[t] += x;
    __syncthreads();
  }
  int run = lds[t] - tsum;   // exclusive prefix of this thread
  for (int j = 0; j < 4; ++j) {
    if (base + j < n) rs[base + j] = run;
    run += v[j];
  }
  if (t == 255) bsum[b] = lds[255];
}

__global__ void scan2_kernel(int* bsum, int nb) {
  if (threadIdx.x == 0 && blockIdx.x == 0) {
    int run = 0;
    for (int i = 0; i < nb; ++i) { int v = bsum[i]; bsum[i] = run; run += v; }
  }
}

__global__ __launch_bounds__(256) void scan3_kernel(int* __restrict__ rs,
                                                    const int* __restrict__ bsum,
                                                    int* __restrict__ cursor, int n) {
  int i = blockIdx.x * 256 + threadIdx.x;
  if (i < n) {
    int v = rs[i] + bsum[i >> 10];
    rs[i] = v;
    cursor[i] = v;
  } else if (i == n) {
    rs[n] = N_EDGES;
  }
}

__global__ __launch_bounds__(256) void scatter_kernel(const int* __restrict__ src,
                                                      const int* __restrict__ dst,
                                                      int* __restrict__ cursor,
                                                      int* __restrict__ csr) {
  int e = blockIdx.x * 256 + threadIdx.x;
  if (e < N_EDGES) {
    int slot = atomicAdd(&cursor[dst[e]], 1);
    csr[slot] = src[e];
  }
}

// ---------------- aggregate (fp8 gather): agg[n] = sum_{e: dst==n} h8[src[e]] ------------
__global__ __launch_bounds__(256) void aggregate8_kernel(const unsigned* __restrict__ h8,
                                                         const int* __restrict__ rs,
                                                         const int* __restrict__ csr,
                                                         __bf16* __restrict__ agg) {
  const int node = blockIdx.x * 4 + (threadIdx.x >> 6);
  if (node >= N_NODES) return;
  const int lane = threadIdx.x & 63;
  const int s = rs[node], e = rs[node + 1];
  float acc[8] = {0.f,0.f,0.f,0.f,0.f,0.f,0.f,0.f};
  const size_t lofs = (size_t)lane * 2;     // 8 fp8 = 2 dwords per lane
  for (int i = s; i < e; i += 4) {
    const int i1 = (i + 1 < e) ? i + 1 : i;
    const int i2 = (i + 2 < e) ? i + 2 : i;
    const int i3 = (i + 3 < e) ? i + 3 : i;
    const float w1 = (i + 1 < e) ? 1.f : 0.f;
    const float w2 = (i + 2 < e) ? 1.f : 0.f;
    const float w3 = (i + 3 < e) ? 1.f : 0.f;
    const int n0 = csr[i], n1 = csr[i1], n2 = csr[i2], n3 = csr[i3];
    uint2 u0 = *(const uint2*)(h8 + (size_t)n0 * 128 + lofs);
    uint2 u1 = *(const uint2*)(h8 + (size_t)n1 * 128 + lofs);
    uint2 u2 = *(const uint2*)(h8 + (size_t)n2 * 128 + lofs);
    uint2 u3 = *(const uint2*)(h8 + (size_t)n3 * 128 + lofs);

    f32x2 a, b, c, d;
    a = __builtin_amdgcn_cvt_pk_f32_fp8((int)u0.x, false);
    b = __builtin_amdgcn_cvt_pk_f32_fp8((int)u0.x, true);
    c = __builtin_amdgcn_cvt_pk_f32_fp8((int)u0.y, false);
    d = __builtin_amdgcn_cvt_pk_f32_fp8((int)u0.y, true);
    acc[0]+=a[0]; acc[1]+=a[1]; acc[2]+=b[0]; acc[3]+=b[1];
    acc[4]+=c[0]; acc[5]+=c[1]; acc[6]+=d[0]; acc[7]+=d[1];

    a = __builtin_amdgcn_cvt_pk_f32_fp8((int)u1.x, false);
    b = __builtin_amdgcn_cvt_pk_f32_fp8((int)u1.x, true);
    c = __builtin_amdgcn_cvt_pk_f32_fp8((int)u1.y, false);
    d = __builtin_amdgcn_cvt_pk_f32_fp8((int)u1.y, true);
    acc[0]=fmaf(w1,a[0],acc[0]); acc[1]=fmaf(w1,a[1],acc[1]);
    acc[2]=fmaf(w1,b[0],acc[2]); acc[3]=fmaf(w1,b[1],acc[3]);
    acc[4]=fmaf(w1,c[0],acc[4]); acc[5]=fmaf(w1,c[1],acc[5]);
    acc[6]=fmaf(w1,d[0],acc[6]); acc[7]=fmaf(w1,d[1],acc[7]);

    a = __builtin_amdgcn_cvt_pk_f32_fp8((int)u2.x, false);
    b = __builtin_amdgcn_cvt_pk_f32_fp8((int)u2.x, true);
    c = __builtin_amdgcn_cvt_pk_f32_fp8((int)u2.y, false);
    d = __builtin_amdgcn_cvt_pk_f32_fp8((int)u2.y, true);
    acc[0]=fmaf(w2,a[0],acc[0]); acc[1]=fmaf(w2,a[1],acc[1]);
    acc[2]=fmaf(w2,b[0],acc[2]); acc[3]=fmaf(w2,b[1],acc[3]);
    acc[4]=fmaf(w2,c[0],acc[4]); acc[5]=fmaf(w2,c[1],acc[5]);
    acc[6]=fmaf(w2,d[0],acc[6]); acc[7]=fmaf(w2,d[1],acc[7]);

    a = __builtin_amdgcn_cvt_pk_f32_fp8((int)u3.x, false);
    b = __builtin_amdgcn_cvt_pk_f32_fp8((int)u3.x, true);
    c = __builtin_amdgcn_cvt_pk_f32_fp8((int)u3.y, false);
    d = __builtin_amdgcn_cvt_pk_f32_fp8((int)u3.y, true);
    acc[0]=fmaf(w3,a[0],acc[0]); acc[1]=fmaf(w3,a[1],acc[1]);
    acc[2]=fmaf(w3,b[0],acc[2]); acc[3]=fmaf(w3,b[1],acc[3]);
    acc[4]=fmaf(w3,c[0],acc[4]); acc[5]=fmaf(w3,c[1],acc[5]);
    acc[6]=fmaf(w3,d[0],acc[6]); acc[7]=fmaf(w3,d[1],acc[7]);
  }
  bf16x8v o;
#pragma unroll
  for (int j = 0; j < 8; ++j) o[j] = (__bf16)acc[j];
  *(bf16x8v*)(agg + (size_t)node * 512 + (size_t)lane * 8) = o;
}

// ---------------- aggregate (layer 1, rank-8): aggS[n] = sum sim0[src] ----------------
__global__ __launch_bounds__(256) void aggsim_kernel(const float* __restrict__ sim,
                                                     const int* __restrict__ rs,
                                                     const int* __restrict__ csr,
                                                     float* __restrict__ aggS) {
  const int node = blockIdx.x * 256 + threadIdx.x;
  if (node >= N_NODES) return;
  f32x4 a0 = f32x4{0.f,0.f,0.f,0.f}, a1 = f32x4{0.f,0.f,0.f,0.f};
  const int s = rs[node], e = rs[node + 1];
  for (int i = s; i < e; ++i) {
    const int sn = csr[i];
    a0 += *(const f32x4*)(sim + (size_t)sn * 8);
    a1 += *(const f32x4*)(sim + (size_t)sn * 8 + 4);
  }
  *(f32x4*)(aggS + (size_t)node * 8) = a0;
  *(f32x4*)(aggS + (size_t)node * 8 + 4) = a1;
}

// ---------------- UV: U[m] = mem0[m] @ W1_1[0:512], V[m] = mem0[m] @ W1_1[512:1024] -----
__global__ __launch_bounds__(512) void uv_kernel(const float* __restrict__ mem,
                                                 const float* __restrict__ w1,
                                                 float* __restrict__ UV) {
  const int mu = blockIdx.x;        // 0..15
  const int c  = threadIdx.x;       // 0..511
  const int m = mu & 7, half = mu >> 3;
  const float* wbase = w1 + (size_t)(half * 512) * 512;
  const float* mrow  = mem + (size_t)m * 512;
  float acc = 0.f;
  for (int k = 0; k < 512; ++k) acc += mrow[k] * wbase[(size_t)k * 512 + c];
  UV[(size_t)mu * 512 + c] = acc;
}

// ---------------- z1y: y1 = relu(sim0 @ U + aggS @ V + b1), [N,512] bf16 ----------------
__global__ __launch_bounds__(256) void z1y_kernel(const float* __restrict__ sim,
                                                  const float* __restrict__ aggS,
                                                  const float* __restrict__ UV,
                                                  const float* __restrict__ b1,
                                                  __bf16* __restrict__ y) {
  __shared__ float suv[16 * 512];   // 32KB
  __shared__ float sb[512];
  const int tid = threadIdx.x;
  for (int i = tid; i < 8192; i += 256) suv[i] = UV[i];
  for (int i = tid; i < 512; i += 256) sb[i] = b1[i];
  __syncthreads();
  const int node = blockIdx.x * 4 + (tid >> 6);
  if (node >= N_NODES) return;
  const int lane = tid & 63;
  f32x4 s0 = *(const f32x4*)(sim + (size_t)node * 8);
  f32x4 s1 = *(const f32x4*)(sim + (size_t)node * 8 + 4);
  f32x4 a0 = *(const f32x4*)(aggS + (size_t)node * 8);
  f32x4 a1 = *(const f32x4*)(aggS + (size_t)node * 8 + 4);
  float sv[8] = {s0[0],s0[1],s0[2],s0[3],s1[0],s1[1],s1[2],s1[3]};
  float av[8] = {a0[0],a0[1],a0[2],a0[3],a1[0],a1[1],a1[2],a1[3]};
  __bf16* yrow = y + (size_t)node * 512;
#pragma unroll
  for (int j = 0; j < 8; ++j) {
    const int c = lane + j * 64;
    float acc = sb[c];
#pragma unroll
    for (int m = 0; m < 8; ++m) {
      acc += sv[m] * suv[m * 512 + c];
      acc += av[m] * suv[(8 + m) * 512 + c];
    }
    yrow[c] = (__bf16)fmaxf(acc, 0.f);
  }
}

// ---------------- GEMM 128x128, BK=32, ring-4 depth-3, 64KB LDS -> 2 blocks/CU ----------
// C[M][512] = relu?( A @ BT^T + bias ), bf16 in/out, fp32 acc.
// H8: epilogue additionally emits fp8-e4m3 copy of C (via LDS repack; ring is dead
// post-loop, guarded by __syncthreads).
template<int KTOT, bool SPLIT, bool RELU, bool H8>
__global__ __launch_bounds__(256, 2) void gemm128_kernel(const __bf16* __restrict__ A1,
                                                         const __bf16* __restrict__ A2,
                                                         const __bf16* __restrict__ BT,
                                                         const float* __restrict__ bias,
                                                         __bf16* __restrict__ C,
                                                         unsigned* __restrict__ C8) {
  extern __shared__ char smem[];
  __bf16* As = (__bf16*)smem;              // 4 slots * 8KB = 32KB
  __bf16* Bs = (__bf16*)(smem + 32768);    // 32KB
  const int tid  = threadIdx.x;
  const int wid  = tid >> 6;     // 0..3
  const int lane = tid & 63;
  const int wm = wid >> 1;       // 0..1
  const int wn = wid & 1;        // 0..1
  const int srow = tid >> 2;     // 0..63 (row within 64-row half)
  const int scol = ((tid & 3) ^ ((tid >> 3) & 3)) * 8;   // inverse-swizzled source chunk
  const int rl  = lane & 15;
  const int rdk = (((lane >> 4) ^ ((lane >> 1) & 3)) * 8);  // swizzled read chunk

  // XCD-aware bijective remap (1564 = 4*196 + 4*195); the 4 N-tiles of a tm share an XCD
  const int bid = blockIdx.x;
  const int xcd = bid & 7, pos = bid >> 3;
  const int idx = (xcd < 4) ? (xcd * 196 + pos) : (784 + (xcd - 4) * 195 + pos);
  const int tm = idx >> 2, tn = idx & 3;

  constexpr int NT = KTOT / 32;

  f32x4 acc[4][4];
#pragma unroll
  for (int mi = 0; mi < 4; ++mi)
#pragma unroll
    for (int ni = 0; ni < 4; ++ni)
      acc[mi][ni] = f32x4{0.f, 0.f, 0.f, 0.f};

  auto stage = [&](int tk) {
    const int slot = tk & 3;
    const __bf16* Ap = A1;
    int kc = tk * 32;
    if (SPLIT && tk >= NT / 2) { Ap = A2; kc -= 512; }
#pragma unroll
    for (int j = 0; j < 2; ++j) {
      const __bf16* g = Ap + (size_t)(tm * 128 + j * 64 + srow) * NH + (kc + scol);
      gload_lds16(g, (char*)As + slot * 8192 + j * 4096 + wid * 1024);
    }
#pragma unroll
    for (int j = 0; j < 2; ++j) {
      const __bf16* g = BT + (size_t)(tn * 128 + j * 64 + srow) * KTOT + (tk * 32 + scol);
      gload_lds16(g, (char*)Bs + slot * 8192 + j * 4096 + wid * 1024);
    }
  };

  // prologue: fill 3 slots (12 loads in flight)
  stage(0); stage(1); stage(2);

  for (int tk = 0; tk < NT; ++tk) {
    if (tk < NT - 2)       asm volatile("s_waitcnt vmcnt(8)" ::: "memory");
    else if (tk == NT - 2) asm volatile("s_waitcnt vmcnt(4)" ::: "memory");
    else                   asm volatile("s_waitcnt vmcnt(0)" ::: "memory");
    __builtin_amdgcn_s_barrier();            // tile tk landed, tile tk-1 consumed
    asm volatile("" ::: "memory");           // pin LDS ops after the barrier

    if (tk + 3 < NT) stage(tk + 3);          // overwrites slot (tk-1)&3 -- safe post-barrier

    const int slot = tk & 3;
    const __bf16* a0 = As + slot * 4096 + (wm * 64 + rl) * 32 + rdk;
    const __bf16* b0 = Bs + slot * 4096 + (wn * 64 + rl) * 32 + rdk;
    bf16x8v av[4], bv[4];
#pragma unroll
    for (int mi = 0; mi < 4; ++mi) av[mi] = *(const bf16x8v*)(a0 + mi * 16 * 32);
#pragma unroll
    for (int ni = 0; ni < 4; ++ni) bv[ni] = *(const bf16x8v*)(b0 + ni * 16 * 32);

    __builtin_amdgcn_s_setprio(1);
#pragma unroll
    for (int mi = 0; mi < 4; ++mi)
#pragma unroll
      for (int ni = 0; ni < 4; ++ni)
        acc[mi][ni] = __builtin_amdgcn_mfma_f32_16x16x32_bf16(av[mi], bv[ni], acc[mi][ni], 0, 0, 0);
    __builtin_amdgcn_s_setprio(0);
  }

  // epilogue: bias (+ relu) -> bf16 (and optionally fp8 via LDS repack)
  __bf16* rep = (__bf16*)smem;    // [128][132] bf16 = 33792B; ring dead after loop
  if (H8) __syncthreads();        // all waves done with ring LDS before overwrite
  const int rg = (lane >> 4) * 4;
#pragma unroll
  for (int ni = 0; ni < 4; ++ni) {
    const int lcol = wn * 64 + ni * 16 + rl;
    const int col = tn * 128 + lcol;
    const float bv_ = bias[col];
#pragma unroll
    for (int mi = 0; mi < 4; ++mi) {
      const int lrowb = wm * 64 + mi * 16 + rg;
      const int rowb = tm * 128 + lrowb;
#pragma unroll
      for (int r = 0; r < 4; ++r) {
        float v = acc[mi][ni][r] + bv_;
        if (RELU) v = fmaxf(v, 0.f);
        const __bf16 bvv = (__bf16)v;
        C[(size_t)(rowb + r) * NH + col] = bvv;
        if (H8) rep[(lrowb + r) * 132 + lcol] = bvv;
      }
    }
  }
  if (H8) {
    __syncthreads();
    const int lrow = tid >> 1;
    const int row_g = tm * 128 + lrow;
    if (row_g < N_NODES) {
      const __bf16* srcp = rep + lrow * 132 + (tid & 1) * 64;
      unsigned dw[16];
#pragma unroll
      for (int q = 0; q < 16; ++q) {
        int w = 0;
        w = __builtin_amdgcn_cvt_pk_fp8_f32((float)srcp[q*4+0], (float)srcp[q*4+1], w, false);
        w = __builtin_amdgcn_cvt_pk_fp8_f32((float)srcp[q*4+2], (float)srcp[q*4+3], w, true);
        dw[q] = (unsigned)w;
      }
      unsigned* dstp = C8 + (size_t)row_g * 128 + (tn * 128 + (tid & 1) * 64) / 4;
#pragma unroll
      for (int q = 0; q < 4; ++q)
        *(uint4*)(dstp + q * 4) = uint4{dw[q*4], dw[q*4+1], dw[q*4+2], dw[q*4+3]};
    }
  }
}

// ---------------- pre-conv GEMM v2: C = x(fp32) @ preT^T + bias, emits bf16 + fp8 --------
// Same ring-4 schedule; A is reg-staged from fp32 x with a 2-SET REGISTER RING (P/Q):
// at iter t, ds_write A(t+3) (loaded 2 iters ago -> latency covered), issue A(t+5) loads.
// A-loads are compiler-tracked (auto vmcnt before the cvt use); manual vmcnt(16) covers
// only the B gload_lds (in-order vmcnt: 16 ops issued after B(t)). lgkmcnt(0) at each
// top-wait publishes the ds_writes across barriers.
__global__ __launch_bounds__(256, 2) void gemmpre2_kernel(const float* __restrict__ X,
                                                          const __bf16* __restrict__ BT,
                                                          const float* __restrict__ bias,
                                                          __bf16* __restrict__ C,
                                                          unsigned* __restrict__ C8) {
  extern __shared__ char smem[];
  __bf16* As = (__bf16*)smem;              // 4 slots * 8KB = 32KB
  __bf16* Bs = (__bf16*)(smem + 32768);    // 32KB
  const int tid  = threadIdx.x;
  const int wid  = tid >> 6;
  const int lane = tid & 63;
  const int wm = wid >> 1, wn = wid & 1;
  const int srow = tid >> 2;
  const int scol = ((tid & 3) ^ ((tid >> 3) & 3)) * 8;
  const int rl  = lane & 15;
  const int rdk = (((lane >> 4) ^ ((lane >> 1) & 3)) * 8);

  const int bid = blockIdx.x;
  const int xcd = bid & 7, pos = bid >> 3;
  const int idx = (xcd < 4) ? (xcd * 196 + pos) : (784 + (xcd - 4) * 195 + pos);
  const int tm = idx >> 2, tn = idx & 3;

  constexpr int NT = 16;   // K = 512

  const int row0 = tm * 128 + srow;
  const int row1 = row0 + 64;
  const bool ok0 = row0 < N_NODES;
  const bool ok1 = row1 < N_NODES;
  const float* xr0 = X + (size_t)row0 * 512 + scol;
  const float* xr1 = X + (size_t)row1 * 512 + scol;
  char* const wbase = (char*)As + wid * 1024 + lane * 16;   // + slot*8192 + j*4096

  struct ASet { f32x4 a0, a1, b0, b1; };
  auto loadA = [&](int tk) -> ASet {
    ASet s;
    const float* p0 = xr0 + tk * 32;
    const float* p1 = xr1 + tk * 32;
    s.a0 = ok0 ? *(const f32x4*)p0       : f32x4{0.f,0.f,0.f,0.f};
    s.a1 = ok0 ? *(const f32x4*)(p0 + 4) : f32x4{0.f,0.f,0.f,0.f};
    s.b0 = ok1 ? *(const f32x4*)p1       : f32x4{0.f,0.f,0.f,0.f};
    s.b1 = ok1 ? *(const f32x4*)(p1 + 4) : f32x4{0.f,0.f,0.f,0.f};
    return s;
  };
  auto writeA = [&](int tk, const ASet& s) {
    const int slot = tk & 3;
    bf16x8v o0, o1;
    o0[0]=(__bf16)s.a0[0]; o0[1]=(__bf16)s.a0[1]; o0[2]=(__bf16)s.a0[2]; o0[3]=(__bf16)s.a0[3];
    o0[4]=(__bf16)s.a1[0]; o0[5]=(__bf16)s.a1[1]; o0[6]=(__bf16)s.a1[2]; o0[7]=(__bf16)s.a1[3];
    o1[0]=(__bf16)s.b0[0]; o1[1]=(__bf16)s.b0[1]; o1[2]=(__bf16)s.b0[2]; o1[3]=(__bf16)s.b0[3];
    o1[4]=(__bf16)s.b1[0]; o1[5]=(__bf16)s.b1[1]; o1[6]=(__bf16)s.b1[2]; o1[7]=(__bf16)s.b1[3];
    *(bf16x8v*)(wbase + slot * 8192)        = o0;
    *(bf16x8v*)(wbase + slot * 8192 + 4096) = o1;
  };
  auto stageB = [&](int tk) {
    const int slot = tk & 3;
#pragma unroll
    for (int j = 0; j < 2; ++j) {
      const __bf16* g = BT + (size_t)(tn * 128 + j * 64 + srow) * NH + (tk * 32 + scol);
      gload_lds16(g, (char*)Bs + slot * 8192 + j * 4096 + wid * 1024);
    }
  };

  f32x4 acc[4][4];
#pragma unroll
  for (int mi = 0; mi < 4; ++mi)
#pragma unroll
    for (int ni = 0; ni < 4; ++ni)
      acc[mi][ni] = f32x4{0.f, 0.f, 0.f, 0.f};

  // prologue: A tiles 0..2 staged with shallow overlap; then B(0..2); then P=A(3), Q=A(4)
  {
    ASet t0 = loadA(0);
    ASet t1 = loadA(1);
    writeA(0, t0);
    ASet t2 = loadA(2);
    writeA(1, t1);
    writeA(2, t2);
  }
  stageB(0); stageB(1); stageB(2);
  ASet P = loadA(3);
  ASet Q = loadA(4);

  for (int tt = 0; tt < NT; tt += 2) {
    // ---- even iteration: set P (odd tiles flow through P) ----
    {
      const int t = tt;
      if (t == 0)            asm volatile("s_waitcnt vmcnt(12) lgkmcnt(0)" ::: "memory");
      else if (t < NT - 3)   asm volatile("s_waitcnt vmcnt(16) lgkmcnt(0)" ::: "memory");
      else                   asm volatile("s_waitcnt vmcnt(0) lgkmcnt(0)" ::: "memory");
      __builtin_amdgcn_s_barrier();
      asm volatile("" ::: "memory");

      if (t + 3 < NT) { writeA(t + 3, P); stageB(t + 3); }
      if (t + 5 < NT) P = loadA(t + 5);

      const int slot = t & 3;
      const __bf16* a0 = As + slot * 4096 + (wm * 64 + rl) * 32 + rdk;
      const __bf16* b0 = Bs + slot * 4096 + (wn * 64 + rl) * 32 + rdk;
      bf16x8v av[4], bv[4];
#pragma unroll
      for (int mi = 0; mi < 4; ++mi) av[mi] = *(const bf16x8v*)(a0 + mi * 16 * 32);
#pragma unroll
      for (int ni = 0; ni < 4; ++ni) bv[ni] = *(const bf16x8v*)(b0 + ni * 16 * 32);
      __builtin_amdgcn_s_setprio(1);
#pragma unroll
      for (int mi = 0; mi < 4; ++mi)
#pragma unroll
        for (int ni = 0; ni < 4; ++ni)
          acc[mi][ni] = __builtin_amdgcn_mfma_f32_16x16x32_bf16(av[mi], bv[ni], acc[mi][ni], 0, 0, 0);
      __builtin_amdgcn_s_setprio(0);
    }
    // ---- odd iteration: set Q ----
    {
      const int t = tt + 1;
      if (t < NT - 3) asm volatile("s_waitcnt vmcnt(16) lgkmcnt(0)" ::: "memory");
      else            asm volatile("s_waitcnt vmcnt(0) lgkmcnt(0)" ::: "memory");
      __builtin_amdgcn_s_barrier();
      asm volatile("" ::: "memory");

      if (t + 3 < NT) { writeA(t + 3, Q); stageB(t + 3); }
      if (t + 5 < NT) Q = loadA(t + 5);

      const int slot = t & 3;
      const __bf16* a0 = As + slot * 4096 + (wm * 64 + rl) * 32 + rdk;
      const __bf16* b0 = Bs + slot * 4096 + (wn * 64 + rl) * 32 + rdk;
      bf16x8v av[4], bv[4];
#pragma unroll
      for (int mi = 0; mi < 4; ++mi) av[mi] = *(const bf16x8v*)(a0 + mi * 16 * 32);
#pragma unroll
      for (int ni = 0; ni < 4; ++ni) bv[ni] = *(const bf16x8v*)(b0 + ni * 16 * 32);
      __builtin_amdgcn_s_setprio(1);
#pragma unroll
      for (int mi = 0; mi < 4; ++mi)
#pragma unroll
        for (int ni = 0; ni < 4; ++ni)
          acc[mi][ni] = __builtin_amdgcn_mfma_f32_16x16x32_bf16(av[mi], bv[ni], acc[mi][ni], 0, 0, 0);
      __builtin_amdgcn_s_setprio(0);
    }
  }

  // epilogue: bias -> bf16 C + fp8 C8 (LDS repack; ring dead post-loop)
  __bf16* rep = (__bf16*)smem;
  __syncthreads();
  const int rg = (lane >> 4) * 4;
#pragma unroll
  for (int ni = 0; ni < 4; ++ni) {
    const int lcol = wn * 64 + ni * 16 + rl;
    const int col = tn * 128 + lcol;
    const float bv_ = bias[col];
#pragma unroll
    for (int mi = 0; mi < 4; ++mi) {
      const int lrowb = wm * 64 + mi * 16 + rg;
      const int rowb = tm * 128 + lrowb;
#pragma unroll
      for (int r = 0; r < 4; ++r) {
        const __bf16 bvv = (__bf16)(acc[mi][ni][r] + bv_);
        C[(size_t)(rowb + r) * NH + col] = bvv;
        rep[(lrowb + r) * 132 + lcol] = bvv;
      }
    }
  }
  __syncthreads();
  const int lrow = tid >> 1;
  const int row_g = tm * 128 + lrow;
  if (row_g < N_NODES) {
    const __bf16* srcp = rep + lrow * 132 + (tid & 1) * 64;
    unsigned dw[16];
#pragma unroll
    for (int q = 0; q < 16; ++q) {
      int w = 0;
      w = __builtin_amdgcn_cvt_pk_fp8_f32((float)srcp[q*4+0], (float)srcp[q*4+1], w, false);
      w = __builtin_amdgcn_cvt_pk_fp8_f32((float)srcp[q*4+2], (float)srcp[q*4+3], w, true);
      dw[q] = (unsigned)w;
    }
    unsigned* dstp = C8 + (size_t)row_g * 128 + (tn * 128 + (tid & 1) * 64) / 4;
#pragma unroll
    for (int q = 0; q < 4; ++q)
      *(uint4*)(dstp + q * 4) = uint4{dw[q*4], dw[q*4+1], dw[q*4+2], dw[q*4+3]};
  }
}

// ---------------- simgemm: simraw[N][8] = h @ mem^T (MFMA, N-dim=16 padded) -------------
__global__ __launch_bounds__(256, 3) void simgemm_kernel(const __bf16* __restrict__ A,
                                                         const __bf16* __restrict__ memT16,
                                                         float* __restrict__ simraw) {
  __shared__ __bf16 As[3 * 128 * 32];    // 24KB ring
  __shared__ __bf16 Bs[16 * 520];        // 16.25KB, padded rows
  const int tid  = threadIdx.x;
  const int wid  = tid >> 6;     // 0..3 (32 rows each)
  const int lane = tid & 63;
  const int srow = tid >> 2;     // 0..63
  const int scol = ((tid & 3) ^ ((tid >> 3) & 3)) * 8;      // inverse-swizzled source chunk
  const int rl  = lane & 15;
  const int rdk = (((lane >> 4) ^ ((lane >> 1) & 3)) * 8);  // swizzled read chunk (A)
  const int k8  = (lane >> 4) * 8;                           // plain chunk (B, padded rows)
  const int tm = blockIdx.x;
  constexpr int NT = 16;         // 512 / 32

  for (int i = tid; i < 16 * 512; i += 256) {
    const int r = i >> 9, c = i & 511;
    Bs[r * 520 + c] = memT16[i];
  }

  f32x4 acc[2];
  acc[0] = f32x4{0.f,0.f,0.f,0.f};
  acc[1] = f32x4{0.f,0.f,0.f,0.f};

  auto stage = [&](int tk) {
    const int slot = tk % 3;
#pragma unroll
    for (int j = 0; j < 2; ++j) {
      const __bf16* g = A + (size_t)(tm * 128 + j * 64 + srow) * NH + (tk * 32 + scol);
      gload_lds16(g, (char*)As + slot * 8192 + j * 4096 + wid * 1024);
    }
  };

  stage(0); stage(1);
  __syncthreads();               // drains Bs ds_writes AND syncs before ring use

  for (int tk = 0; tk < NT; ++tk) {
    if (tk < NT - 1) asm volatile("s_waitcnt vmcnt(2)" ::: "memory");
    else             asm volatile("s_waitcnt vmcnt(0)" ::: "memory");
    __builtin_amdgcn_s_barrier();
    asm volatile("" ::: "memory");

    if (tk + 2 < NT) stage(tk + 2);

    const int slot = tk % 3;
    const __bf16* a0 = As + slot * 4096 + (wid * 32 + rl) * 32 + rdk;
    bf16x8v av0 = *(const bf16x8v*)(a0);
    bf16x8v av1 = *(const bf16x8v*)(a0 + 16 * 32);
    bf16x8v bv  = *(const bf16x8v*)(Bs + rl * 520 + tk * 32 + k8);
    acc[0] = __builtin_amdgcn_mfma_f32_16x16x32_bf16(av0, bv, acc[0], 0, 0, 0);
    acc[1] = __builtin_amdgcn_mfma_f32_16x16x32_bf16(av1, bv, acc[1], 0, 0, 0);
  }

  const int rg = (lane >> 4) * 4;
  if (rl < 8) {
#pragma unroll
    for (int mi = 0; mi < 2; ++mi) {
      const int rowb = tm * 128 + wid * 32 + mi * 16 + rg;
#pragma unroll
      for (int r = 0; r < 4; ++r) {
        const int row = rowb + r;
        if (row < N_NODES) simraw[(size_t)row * 8 + rl] = acc[mi][r];
      }
    }
  }
}

// ---------------- smpool: softmax(simraw) -> (sim0?) + pooling of sim@mem ----------------
template<bool WRITE_SIM>
__global__ __launch_bounds__(256) void smpool_kernel(const float* __restrict__ simraw,
                                                     const float* __restrict__ mem,
                                                     const int* __restrict__ batch,
                                                     unsigned* __restrict__ gmax,
                                                     float* __restrict__ gsum,
                                                     int colofs,
                                                     float* __restrict__ simout) {
  __shared__ float sm[8 * 512];
  const int tid = threadIdx.x;
  for (int i = tid; i < 4096; i += 256) sm[i] = mem[i];
  __syncthreads();
  const int lane = tid & 63;
  const int n0 = blockIdx.x * 128 + (tid >> 6) * 32;
  const int nend = min(n0 + 32, N_NODES);

  float mx[8], sv[8];
#pragma unroll
  for (int j = 0; j < 8; ++j) { mx[j] = -3.0e38f; sv[j] = 0.f; }
  int cur = -1;

  for (int n = n0; n < nend; ++n) {
    const int g = batch[n];
    if (g != cur) {
      if (cur >= 0) {
#pragma unroll
        for (int j = 0; j < 8; ++j) {
          atomicMax(&gmax[(size_t)cur * 1024 + colofs + lane + j * 64], enc_f32(mx[j]));
          atomicAdd(&gsum[(size_t)cur * 1024 + colofs + lane + j * 64], sv[j]);
        }
      }
      cur = g;
#pragma unroll
      for (int j = 0; j < 8; ++j) { mx[j] = -3.0e38f; sv[j] = 0.f; }
    }
    f32x4 r0 = *(const f32x4*)(simraw + (size_t)n * 8);
    f32x4 r1 = *(const f32x4*)(simraw + (size_t)n * 8 + 4);
    float w[8] = {r0[0],r0[1],r0[2],r0[3],r1[0],r1[1],r1[2],r1[3]};
    float smx = w[0];
#pragma unroll
    for (int m = 1; m < 8; ++m) smx = fmaxf(smx, w[m]);
    float ssum = 0.f;
#pragma unroll
    for (int m = 0; m < 8; ++m) { w[m] = __expf(w[m] - smx); ssum += w[m]; }
    const float inv = 1.f / ssum;
#pragma unroll
    for (int m = 0; m < 8; ++m) w[m] *= inv;
    if (WRITE_SIM && lane == 0) {
      f32x4 o0{w[0], w[1], w[2], w[3]};
      f32x4 o1{w[4], w[5], w[6], w[7]};
      *(f32x4*)(simout + (size_t)n * 8) = o0;
      *(f32x4*)(simout + (size_t)n * 8 + 4) = o1;
    }
    float outv[8] = {0.f,0.f,0.f,0.f,0.f,0.f,0.f,0.f};
#pragma unroll
    for (int m = 0; m < 8; ++m) {
      const float wm_ = w[m];
      const float* mr = sm + m * 512 + lane;
#pragma unroll
      for (int j = 0; j < 8; ++j) outv[j] += wm_ * mr[j * 64];
    }
#pragma unroll
    for (int j = 0; j < 8; ++j) {
      mx[j] = fmaxf(mx[j], outv[j]);
      sv[j] += outv[j];
    }
  }
  if (cur >= 0) {
#pragma unroll
    for (int j = 0; j < 8; ++j) {
      atomicMax(&gmax[(size_t)cur * 1024 + colofs + lane + j * 64], enc_f32(mx[j]));
      atomicAdd(&gsum[(size_t)cur * 1024 + colofs + lane + j * 64], sv[j]);
    }
  }
}

// ---------------- graph ranges (batch is sorted) ----------------
__global__ __launch_bounds__(256) void ranges_kernel(const int* __restrict__ batch,
                                                     int* __restrict__ gstart) {
  int g = blockIdx.x * 256 + threadIdx.x;
  if (g > N_GRAPH) return;
  if (g == N_GRAPH) { gstart[N_GRAPH] = N_NODES; return; }
  int lo = 0, hi = N_NODES;
  while (lo < hi) {
    int mid = (lo + hi) >> 1;
    if (batch[mid] < g) lo = mid + 1; else hi = mid;
  }
  gstart[g] = lo;
}

// ---------------- pooling decode: gf [G][2048] = [max | mean] ----------------
__global__ __launch_bounds__(256) void pool2_kernel(const unsigned* __restrict__ gmax,
                                                    const float* __restrict__ gsum,
                                                    const int* __restrict__ gstart,
                                                    float* __restrict__ g) {
  const int gr = blockIdx.x;
  const int t = threadIdx.x;
  const int cnt = gstart[gr + 1] - gstart[gr];
  const float inv = 1.f / fmaxf((float)cnt, 1.f);
#pragma unroll
  for (int j = 0; j < 4; ++j) {
    const int f = t * 4 + j;
    unsigned u = gmax[(size_t)gr * 1024 + f];
    g[(size_t)gr * 2048 + f] = (cnt > 0) ? dec_f32(u) : 0.f;
    g[(size_t)gr * 2048 + 1024 + f] = gsum[(size_t)gr * 1024 + f] * inv;
  }
}

// ---------------- classifier head: log_softmax(g @ lin_w + lin_b) ----------------
__global__ __launch_bounds__(64) void classify_kernel(const float* __restrict__ g,
                                                      const float* __restrict__ lw,
                                                      const float* __restrict__ lb,
                                                      float* __restrict__ out) {
  const int gr = blockIdx.x;
  const int lane = threadIdx.x;   // 64
  float acc[10];
  for (int c = 0; c < 10; ++c) acc[c] = 0.f;
  const float* grow = g + (size_t)gr * 2048;
  for (int k = lane; k < 2048; k += 64) {
    float gv = grow[k];
    const float* w = lw + (size_t)k * 10;
#pragma unroll
    for (int c = 0; c < 10; ++c) acc[c] += gv * w[c];
  }
  for (int c = 0; c < 10; ++c)
    for (int off = 32; off; off >>= 1) acc[c] += __shfl_xor(acc[c], off, 64);
  if (lane == 0) {
    float lg[10];
    float mx = -3.0e38f;
    for (int c = 0; c < 10; ++c) { lg[c] = acc[c] + lb[c]; mx = fmaxf(mx, lg[c]); }
    float s = 0.f;
    for (int c = 0; c < 10; ++c) s += expf(lg[c] - mx);
    float lse = logf(s);
    for (int c = 0; c < 10; ++c) out[(size_t)gr * 10 + c] = lg[c] - mx - lse;
  }
}

// =======================================================================================
extern "C" void kernel_launch(void* const* d_in, const int* in_sizes, int n_in,
                              void* d_out, int out_size, void* d_ws, size_t ws_size,
                              hipStream_t stream) {
  (void)in_sizes; (void)n_in; (void)out_size; (void)ws_size;
  const float* x      = (const float*)d_in[0];
  const int*   eidx   = (const int*)d_in[1];
  const int*   batch  = (const int*)d_in[2];
  const float* pre_w  = (const float*)d_in[4];
  const float* pre_b  = (const float*)d_in[5];
  const float* w1_0   = (const float*)d_in[6];
  const float* b1_0   = (const float*)d_in[7];
  const float* w2_0   = (const float*)d_in[8];
  const float* b2_0   = (const float*)d_in[9];
  const float* mem_0  = (const float*)d_in[10];
  const float* w1_1   = (const float*)d_in[11];
  const float* b1_1   = (const float*)d_in[12];
  const float* w2_1   = (const float*)d_in[13];
  const float* b2_1   = (const float*)d_in[14];
  const float* mem_1  = (const float*)d_in[15];
  const float* lin_w  = (const float*)d_in[16];
  const float* lin_b  = (const float*)d_in[17];
  float* out = (float*)d_out;

  const int* src = eidx;
  const int* dst = eidx + N_EDGES;

  // ---- workspace carve ----
  char* p = (char*)d_ws;
  auto alloc = [&](size_t bytes) -> char* {
    char* r = p;
    p += (bytes + 255) & ~(size_t)255;
    return r;
  };
  __bf16* hb    = (__bf16*)alloc((size_t)MP * 512 * 2);
  __bf16* aggb  = (__bf16*)alloc((size_t)MP * 512 * 2);
  __bf16* y1b   = (__bf16*)alloc((size_t)MP * 512 * 2);
  unsigned* h8  = (unsigned*)alloc((size_t)N_NODES * 512);
  __bf16* preT  = (__bf16*)alloc((size_t)512 * 512 * 2);
  __bf16* w1T0  = (__bf16*)alloc((size_t)512 * 1024 * 2);
  __bf16* w2T0  = (__bf16*)alloc((size_t)512 * 512 * 2);
  __bf16* w2T1  = (__bf16*)alloc((size_t)512 * 512 * 2);
  __bf16* memT0 = (__bf16*)alloc((size_t)16 * 512 * 2);
  __bf16* memT1 = (__bf16*)alloc((size_t)16 * 512 * 2);
  int* deg      = (int*)alloc((size_t)N_NODES * 4);
  int* rowstart = (int*)alloc((size_t)(N_NODES + 1) * 4);
  int* cursor   = (int*)alloc((size_t)N_NODES * 4);
  int* bsum     = (int*)alloc(128 * 4);
  int* csr      = (int*)alloc((size_t)N_EDGES * 4);
  int* gstart   = (int*)alloc((size_t)(N_GRAPH + 1) * 4);
  float* gf     = (float*)alloc((size_t)N_GRAPH * 2048 * 4);
  unsigned* gmax = (unsigned*)alloc((size_t)N_GRAPH * 1024 * 4);
  float* gsum    = (float*)alloc((size_t)N_GRAPH * 1024 * 4);
  float* sim0    = (float*)alloc((size_t)N_NODES * 8 * 4);
  float* simraw  = (float*)alloc((size_t)N_NODES * 8 * 4);
  float* aggS    = (float*)alloc((size_t)N_NODES * 8 * 4);
  float* UV      = (float*)alloc((size_t)16 * 512 * 4);

  // ---- dynamic LDS (64KB, ring-4) for the GEMM instantiations ----
  const int GEMM_LDS = 65536;
  hipFuncSetAttribute(reinterpret_cast<const void*>(&gemmpre2_kernel),
                      hipFuncAttributeMaxDynamicSharedMemorySize, GEMM_LDS);
  hipFuncSetAttribute(reinterpret_cast<const void*>(&gemm128_kernel<1024, true,  true,  false>),
                      hipFuncAttributeMaxDynamicSharedMemorySize, GEMM_LDS);
  hipFuncSetAttribute(reinterpret_cast<const void*>(&gemm128_kernel<512,  false, true,  false>),
                      hipFuncAttributeMaxDynamicSharedMemorySize, GEMM_LDS);

  // ---- weight prep ----
  transpose_kernel<<<dim3(16, 16), 256, 0, stream>>>(pre_w, preT, 512, 512);
  transpose_kernel<<<dim3(16, 32), 256, 0, stream>>>(w1_0, w1T0, 1024, 512);
  transpose_kernel<<<dim3(16, 16), 256, 0, stream>>>(w2_0, w2T0, 512, 512);
  transpose_kernel<<<dim3(16, 16), 256, 0, stream>>>(w2_1, w2T1, 512, 512);
  castmem_kernel<<<16, 256, 0, stream>>>(mem_0, memT0);
  castmem_kernel<<<16, 256, 0, stream>>>(mem_1, memT1);
  uv_kernel<<<16, 512, 0, stream>>>(mem_0, w1_1, UV);   // rank-8 tables for layer 1

  // ---- CSR build (per call; deterministic work) ----
  hipMemsetAsync(deg, 0, (size_t)N_NODES * 4, stream);
  degree_kernel<<<3125, 256, 0, stream>>>(dst, deg);
  scan1_kernel<<<98, 256, 0, stream>>>(deg, rowstart, bsum, N_NODES);
  scan2_kernel<<<1, 64, 0, stream>>>(bsum, 98);
  scan3_kernel<<<392, 256, 0, stream>>>(rowstart, bsum, cursor, N_NODES);
  scatter_kernel<<<3125, 256, 0, stream>>>(src, dst, cursor, csr);

  // pooling accumulators: gmax||gsum are contiguous -> one memset
  hipMemsetAsync(gmax, 0, (size_t)N_GRAPH * 1024 * 4 * 2, stream);
  ranges_kernel<<<2, 256, 0, stream>>>(batch, gstart);

  const int GG = 1564;   // 391 M-tiles x 4 N-tiles

  // ---- pre conv: h = x @ pre_w + pre_b (reads x fp32 directly; emits bf16 + fp8) ----
  gemmpre2_kernel<<<GG, 256, GEMM_LDS, stream>>>(x, preT, pre_b, hb, h8);

  // ---- layer 0 ----
  aggregate8_kernel<<<25000, 256, 0, stream>>>(h8, rowstart, csr, aggb);
  gemm128_kernel<1024, true, true, false><<<GG, 256, GEMM_LDS, stream>>>(
      hb, aggb, w1T0, b1_0, y1b, nullptr);
  gemm128_kernel<512, false, true, false><<<GG, 256, GEMM_LDS, stream>>>(
      y1b, nullptr, w2T0, b2_0, hb, nullptr);
  simgemm_kernel<<<391, 256, 0, stream>>>(hb, memT0, simraw);
  smpool_kernel<true><<<782, 256, 0, stream>>>(simraw, mem_0, batch, gmax, gsum, 0, sim0);

  // ---- layer 1 (rank-8 collapsed front half) ----
  aggsim_kernel<<<391, 256, 0, stream>>>(sim0, rowstart, csr, aggS);
  z1y_kernel<<<25000, 256, 0, stream>>>(sim0, aggS, UV, b1_1, y1b);
  gemm128_kernel<512, false, true, false><<<GG, 256, GEMM_LDS, stream>>>(
      y1b, nullptr, w2T1, b2_1, hb, nullptr);
  simgemm_kernel<<<391, 256, 0, stream>>>(hb, memT1, simraw);
  smpool_kernel<false><<<782, 256, 0, stream>>>(simraw, mem_1, batch, gmax, gsum, 512, nullptr);

  // ---- readout ----
  pool2_kernel<<<N_GRAPH, 256, 0, stream>>>(gmax, gsum, gstart, gf);
  classify_kernel<<<N_GRAPH, 64, 0, stream>>>(gf, lin_w, lin_b, out);
}